// Round 14
// baseline (826.158 us; speedup 1.0000x reference)
//
#include <hip/hip_runtime.h>

typedef unsigned short ushort_t;
typedef __attribute__((ext_vector_type(8))) __bf16 bf16x8;
typedef __attribute__((ext_vector_type(8))) unsigned short ushort8;
typedef __attribute__((ext_vector_type(4))) unsigned short ushort4v;
typedef __attribute__((ext_vector_type(4))) float f32x4;

#define N_NODES 8192
#define NODE_MASK 8191
#define E_EDGES 32768
#define E_TOT   40960   /* E + N self loops */
#define M_MASK  2048
#define D_IN    768
#define C_CH    768
#define F1      6144    /* 8 heads * 768 */

typedef __attribute__((address_space(1))) const void* gas_ptr;
typedef __attribute__((address_space(3))) void* las_ptr;

__device__ __forceinline__ float bf2f(ushort_t u) {
    union { unsigned int i; float f; } v; v.i = ((unsigned int)u) << 16; return v.f;
}
__device__ __forceinline__ ushort_t f2bf(float f) {
    union { float f; unsigned int i; } v; v.f = f;
    unsigned int r = v.i + 0x7fffu + ((v.i >> 16) & 1u);
    return (ushort_t)(r >> 16);
}

// ---------------------------------------------------------------------------
// int64-vs-int32 detection + conversion of index arrays (clamped to [0,N)).
// detect/convert each merged into one launch for both arrays.
// ---------------------------------------------------------------------------
__global__ void init_kernel(int* deg, int* fill, int* flags) {
    int i = blockIdx.x * 256 + threadIdx.x;
    if (i < N_NODES) { deg[i] = 0; fill[i] = 0; }
    if (i < 2) flags[i] = 0;
}
__global__ void detect2_kernel(const int* __restrict__ raw_e, const int* __restrict__ raw_m,
                               int* __restrict__ flags) {
    int i = blockIdx.x * 256 + threadIdx.x;
    if (i < E_EDGES) {
        if (raw_e[2 * i + 1] != 0) atomicOr(&flags[0], 1);
    } else {
        int j = i - E_EDGES;
        if (j < M_MASK / 2 && raw_m[2 * j + 1] != 0) atomicOr(&flags[1], 1);
    }
}
__global__ void convert2_kernel(const void* __restrict__ ei_raw, const void* __restrict__ mask_raw,
                                const int* __restrict__ flags,
                                int* __restrict__ eic, int* __restrict__ maskc) {
    int i = blockIdx.x * 256 + threadIdx.x;
    if (i < 2 * E_EDGES) {
        int v = flags[0] ? ((const int*)ei_raw)[i] : (int)((const long long*)ei_raw)[i];
        eic[i] = v & NODE_MASK;
    } else {
        int j = i - 2 * E_EDGES;
        if (j < M_MASK) {
            int v = flags[1] ? ((const int*)mask_raw)[j] : (int)((const long long*)mask_raw)[j];
            maskc[j] = v & NODE_MASK;
        }
    }
}

// ---------------------------------------------------------------------------
// f32 -> bf16 elementwise convert (vectorized)
// ---------------------------------------------------------------------------
__global__ void cvt_bf16_kernel(const float* __restrict__ in, ushort_t* __restrict__ out, int n4) {
    int i = blockIdx.x * 256 + threadIdx.x;
    if (i >= n4) return;
    f32x4 v = *(const f32x4*)(in + i * 4);
    ushort_t o0 = f2bf(v[0]), o1 = f2bf(v[1]), o2 = f2bf(v[2]), o3 = f2bf(v[3]);
    unsigned long long pk = (unsigned long long)o0 | ((unsigned long long)o1 << 16)
                          | ((unsigned long long)o2 << 32) | ((unsigned long long)o3 << 48);
    *(unsigned long long*)(out + i * 4) = pk;
}

// ---------------------------------------------------------------------------
// f32 -> bf16 transpose: out[c][r] = (bf16)in[r][c]; in is R x Ccols f32.
// ---------------------------------------------------------------------------
__global__ __launch_bounds__(256) void transpose_cvt_kernel(
    const float* __restrict__ in, ushort_t* __restrict__ out, int R, int Ccols)
{
    __shared__ ushort_t tile[32][33];
    int tx = threadIdx.x & 31, ty = threadIdx.x >> 5;
    int x  = blockIdx.x * 32 + tx;
    int y0 = blockIdx.y * 32;
#pragma unroll
    for (int i = 0; i < 4; ++i)
        tile[ty + i * 8][tx] = f2bf(in[(size_t)(y0 + ty + i * 8) * Ccols + x]);
    __syncthreads();
#pragma unroll
    for (int i = 0; i < 4; ++i)
        out[(size_t)(blockIdx.x * 32 + ty + i * 8) * R + y0 + tx] = tile[tx][ty + i * 8];
}

// ---------------------------------------------------------------------------
// bf16 MFMA GEMM:  C[M,N] = A[M,K] * Bt[N,K]^T  (+ optional f32 bias[N]) -> bf16
// 128x128 tile, BK=64, 256 threads (m97 structure, 84 VGPR). Used for head GEMM.
// ---------------------------------------------------------------------------
__global__ __launch_bounds__(256) void gemm_bt_kernel(
    const ushort_t* __restrict__ A, const ushort_t* __restrict__ Bt,
    ushort_t* __restrict__ C, const float* __restrict__ bias,
    int M, int N, int K)
{
    __shared__ ushort_t lsA[128 * 64];
    __shared__ ushort_t lsB[128 * 64];

    const int tid  = threadIdx.x;
    const int lane = tid & 63;
    const int wave = tid >> 6;
    const int wm = wave >> 1, wn = wave & 1;
    const int bx = blockIdx.x, by = blockIdx.y;

    const f32x4 zero = {0.f, 0.f, 0.f, 0.f};
    f32x4 acc[4][4];
#pragma unroll
    for (int i = 0; i < 4; ++i)
#pragma unroll
        for (int j = 0; j < 4; ++j) acc[i][j] = zero;

    const int l8 = lane >> 3;   // row within 8-row group
    const int c8 = lane & 7;    // 16B chunk slot
    const int q  = lane >> 4;   // quad
    const int rl = lane & 15;

    for (int kt = 0; kt < K; kt += 64) {
        __syncthreads();   // previous tile fully consumed
#pragma unroll
        for (int i = 0; i < 4; ++i) {
            int rbase = wave * 32 + i * 8;      // wave-uniform
            int row   = rbase + l8;             // per-lane
            int gch   = c8 ^ (row & 7);         // swizzle on source
            const ushort_t* gA = A  + (size_t)(by * 128 + row) * K + kt + gch * 8;
            const ushort_t* gB = Bt + (size_t)(bx * 128 + row) * K + kt + gch * 8;
            __builtin_amdgcn_global_load_lds((gas_ptr)gA, (las_ptr)(lsA + rbase * 64), 16, 0, 0);
            __builtin_amdgcn_global_load_lds((gas_ptr)gB, (las_ptr)(lsB + rbase * 64), 16, 0, 0);
        }
        __syncthreads();   // vmcnt drained by barrier semantics
#pragma unroll
        for (int s = 0; s < 2; ++s) {
            bf16x8 af[4], bfv[4];
#pragma unroll
            for (int i = 0; i < 4; ++i) {
                int Ra = wm * 64 + i * 16 + rl;
                af[i]  = *(const bf16x8*)(lsA + Ra * 64 + (((s * 4 + q) ^ (Ra & 7)) * 8));
                int Rb = wn * 64 + i * 16 + rl;
                bfv[i] = *(const bf16x8*)(lsB + Rb * 64 + (((s * 4 + q) ^ (Rb & 7)) * 8));
            }
#pragma unroll
            for (int i = 0; i < 4; ++i)
#pragma unroll
                for (int j = 0; j < 4; ++j)
                    acc[i][j] = __builtin_amdgcn_mfma_f32_16x16x32_bf16(af[i], bfv[j], acc[i][j], 0, 0, 0);
        }
    }
    // epilogue: C/D layout col=lane&15, row=quad*4+reg (m89-verified)
#pragma unroll
    for (int j = 0; j < 4; ++j) {
        int col = bx * 128 + wn * 64 + j * 16 + rl;
        float bv = bias ? bias[col] : 0.0f;
#pragma unroll
        for (int i = 0; i < 4; ++i) {
#pragma unroll
            for (int t = 0; t < 4; ++t) {
                int row = by * 128 + wm * 64 + i * 16 + q * 4 + t;
                C[(size_t)row * N + col] = f2bf(acc[i][j][t] + bv);
            }
        }
    }
}

// ---------------------------------------------------------------------------
// Per-head block-diagonal GEMM for layer 1 (aggregate-then-project algebra):
//   out1[n, h*768+c] = ELU( b1[h*768+c] + xagg_h[n,:] @ W1t[h*768+c,:] )
// Linear grid of 3072 blocks with XCD-aware panel-grouping decode; head==xcd
// so each XCD's W1t panel + xagg slice stay L2-resident (FETCH 314->66MB).
// bias+ELU fused in-place on acc.
// ---------------------------------------------------------------------------
#define NBX_BD 6     /* 768/128 */
#define NBY_BD 64    /* 8192/128 */

__global__ __launch_bounds__(256) void gemm_bd_kernel(
    const ushort_t* __restrict__ A0, const ushort_t* __restrict__ Bt0,
    ushort_t* __restrict__ C, const float* __restrict__ bias,
    int M, int K)
{
    __shared__ ushort_t lsA[128 * 64];
    __shared__ ushort_t lsB[128 * 64];

    const int tid  = threadIdx.x;
    const int lane = tid & 63;
    const int wave = tid >> 6;
    const int wm = wave >> 1, wn = wave & 1;

    // XCD-aware bijective decode (3072 blocks, 8 XCDs, 64 panel-groups/XCD)
    const int d    = blockIdx.x;
    const int xcd  = d & 7;
    const int slot = d >> 3;                 // 0..383
    const int bx   = slot % NBX_BD;          // 0..5
    const int grp  = xcd * 64 + slot / NBX_BD;   // 0..511
    const int by   = grp & (NBY_BD - 1);
    const int head = grp >> 6;               // == xcd

    const ushort_t* A  = A0  + (size_t)head * M * K;
    const ushort_t* Bt = Bt0 + (size_t)head * C_CH * K;

    const f32x4 zero = {0.f, 0.f, 0.f, 0.f};
    f32x4 acc[4][4];
#pragma unroll
    for (int i = 0; i < 4; ++i)
#pragma unroll
        for (int j = 0; j < 4; ++j) acc[i][j] = zero;

    const int l8 = lane >> 3;
    const int c8 = lane & 7;
    const int q  = lane >> 4;
    const int rl = lane & 15;

    for (int kt = 0; kt < K; kt += 64) {
        __syncthreads();
#pragma unroll
        for (int i = 0; i < 4; ++i) {
            int rbase = wave * 32 + i * 8;
            int row   = rbase + l8;
            int gch   = c8 ^ (row & 7);
            const ushort_t* gA = A  + (size_t)(by * 128 + row) * K + kt + gch * 8;
            const ushort_t* gB = Bt + (size_t)(bx * 128 + row) * K + kt + gch * 8;
            __builtin_amdgcn_global_load_lds((gas_ptr)gA, (las_ptr)(lsA + rbase * 64), 16, 0, 0);
            __builtin_amdgcn_global_load_lds((gas_ptr)gB, (las_ptr)(lsB + rbase * 64), 16, 0, 0);
        }
        __syncthreads();
#pragma unroll
        for (int s = 0; s < 2; ++s) {
            bf16x8 af[4], bfv[4];
#pragma unroll
            for (int i = 0; i < 4; ++i) {
                int Ra = wm * 64 + i * 16 + rl;
                af[i]  = *(const bf16x8*)(lsA + Ra * 64 + (((s * 4 + q) ^ (Ra & 7)) * 8));
                int Rb = wn * 64 + i * 16 + rl;
                bfv[i] = *(const bf16x8*)(lsB + Rb * 64 + (((s * 4 + q) ^ (Rb & 7)) * 8));
            }
#pragma unroll
            for (int i = 0; i < 4; ++i)
#pragma unroll
                for (int j = 0; j < 4; ++j)
                    acc[i][j] = __builtin_amdgcn_mfma_f32_16x16x32_bf16(af[i], bfv[j], acc[i][j], 0, 0, 0);
        }
    }
    // epilogue: bias + ELU fused, store into the full 6144-wide out1
#pragma unroll
    for (int j = 0; j < 4; ++j) {
        int colf = head * C_CH + bx * 128 + wn * 64 + j * 16 + rl;
        float bv = bias[colf];
#pragma unroll
        for (int i = 0; i < 4; ++i) {
#pragma unroll
            for (int t = 0; t < 4; ++t) {
                int row = by * 128 + wm * 64 + i * 16 + q * 4 + t;
                float v = acc[i][j][t] + bv;
                v = v > 0.f ? v : (__expf(v) - 1.0f);   // ELU
                C[(size_t)row * F1 + colf] = f2bf(v);
            }
        }
    }
}

// ---------------------------------------------------------------------------
// Split-K variant for the N=768 layer-2 GEMM, NSPLIT=4, bf16 partials.
// 1536 blocks = 6/CU dispatched (vs 3 at NSPLIT=2) for better latency
// hiding; bf16 partials keep total partial traffic identical to the old
// f32 x2 scheme (48MB write + 48MB read). XCD decode: all 6 bx-blocks of
// one A-panel on one XCD; grp = xcd*32 + slot/6; by=grp&63, bz=grp>>6.
// ---------------------------------------------------------------------------
#define NBX2 6      /* N=768 / 128 */
#define NBY2 64     /* M=8192 / 128 */
#define NSPLIT 4

__global__ __launch_bounds__(256) void gemm_bt_splitk_kernel(
    const ushort_t* __restrict__ A, const ushort_t* __restrict__ Bt,
    ushort_t* __restrict__ Cpart, int M, int N, int K)
{
    __shared__ ushort_t lsA[128 * 64];
    __shared__ ushort_t lsB[128 * 64];

    const int tid  = threadIdx.x;
    const int lane = tid & 63;
    const int wave = tid >> 6;
    const int wm = wave >> 1, wn = wave & 1;

    // XCD-aware bijective decode (1536 blocks, 8 XCDs, 32 panel-groups/XCD)
    const int d    = blockIdx.x;
    const int xcd  = d & 7;
    const int slot = d >> 3;                  // 0..191
    const int bx   = slot % NBX2;             // 0..5
    const int grp  = xcd * 32 + slot / NBX2;  // 0..255
    const int by   = grp & (NBY2 - 1);        // 0..63
    const int bz   = grp >> 6;                // 0..3

    const int kh  = K >> 2;
    const int kt0 = bz * kh;
    ushort_t* __restrict__ Cp = Cpart + (size_t)bz * M * N;

    const f32x4 zero = {0.f, 0.f, 0.f, 0.f};
    f32x4 acc[4][4];
#pragma unroll
    for (int i = 0; i < 4; ++i)
#pragma unroll
        for (int j = 0; j < 4; ++j) acc[i][j] = zero;

    const int l8 = lane >> 3;
    const int c8 = lane & 7;
    const int q  = lane >> 4;
    const int rl = lane & 15;

    for (int kt = kt0; kt < kt0 + kh; kt += 64) {
        __syncthreads();
#pragma unroll
        for (int i = 0; i < 4; ++i) {
            int rbase = wave * 32 + i * 8;
            int row   = rbase + l8;
            int gch   = c8 ^ (row & 7);
            const ushort_t* gA = A  + (size_t)(by * 128 + row) * K + kt + gch * 8;
            const ushort_t* gB = Bt + (size_t)(bx * 128 + row) * K + kt + gch * 8;
            __builtin_amdgcn_global_load_lds((gas_ptr)gA, (las_ptr)(lsA + rbase * 64), 16, 0, 0);
            __builtin_amdgcn_global_load_lds((gas_ptr)gB, (las_ptr)(lsB + rbase * 64), 16, 0, 0);
        }
        __syncthreads();
#pragma unroll
        for (int s = 0; s < 2; ++s) {
            bf16x8 af[4], bfv[4];
#pragma unroll
            for (int i = 0; i < 4; ++i) {
                int Ra = wm * 64 + i * 16 + rl;
                af[i]  = *(const bf16x8*)(lsA + Ra * 64 + (((s * 4 + q) ^ (Ra & 7)) * 8));
                int Rb = wn * 64 + i * 16 + rl;
                bfv[i] = *(const bf16x8*)(lsB + Rb * 64 + (((s * 4 + q) ^ (Rb & 7)) * 8));
            }
#pragma unroll
            for (int i = 0; i < 4; ++i)
#pragma unroll
                for (int j = 0; j < 4; ++j)
                    acc[i][j] = __builtin_amdgcn_mfma_f32_16x16x32_bf16(af[i], bfv[j], acc[i][j], 0, 0, 0);
        }
    }
#pragma unroll
    for (int j = 0; j < 4; ++j) {
        int col = bx * 128 + wn * 64 + j * 16 + rl;
#pragma unroll
        for (int i = 0; i < 4; ++i) {
#pragma unroll
            for (int t = 0; t < 4; ++t) {
                int row = by * 128 + wm * 64 + i * 16 + q * 4 + t;
                Cp[(size_t)row * N + col] = f2bf(acc[i][j][t]);
            }
        }
    }
}

// ---------------------------------------------------------------------------
// Split-K reduce (4 bf16 partials) + fused layer-2 attention logits.
// One 192-thread block per node: h2[n] = sum_k Pk[n] -> bf16, and
// a_s2/a_d2 via block reduce. No atomics.
// ---------------------------------------------------------------------------
__global__ __launch_bounds__(192) void splitk_reduce_att_kernel(
    const ushort_t* __restrict__ P, ushort_t* __restrict__ out,
    const float* __restrict__ as2, const float* __restrict__ ad2,
    float* __restrict__ a_s, float* __restrict__ a_d)
{
    const int n = blockIdx.x, tid = threadIdx.x;
    const int c0 = tid * 4;
    float v[4] = {0.f, 0.f, 0.f, 0.f};
#pragma unroll
    for (int k = 0; k < NSPLIT; ++k) {
        ushort4v p = *(const ushort4v*)(P + ((size_t)k * N_NODES + n) * C_CH + c0);
#pragma unroll
        for (int t = 0; t < 4; ++t) v[t] += bf2f(p[t]);
    }
    f32x4 ws = *(const f32x4*)(as2 + c0);
    f32x4 wd = *(const f32x4*)(ad2 + c0);
    float s1 = 0.f, s2 = 0.f;
    ushort_t o[4];
#pragma unroll
    for (int t = 0; t < 4; ++t) {
        o[t] = f2bf(v[t]);
        s1 += v[t] * ws[t];
        s2 += v[t] * wd[t];
    }
    unsigned long long pk = (unsigned long long)o[0] | ((unsigned long long)o[1] << 16)
                          | ((unsigned long long)o[2] << 32) | ((unsigned long long)o[3] << 48);
    *(unsigned long long*)(out + (size_t)n * C_CH + c0) = pk;

    __shared__ float red[2][3];
#pragma unroll
    for (int off = 32; off > 0; off >>= 1) {
        s1 += __shfl_down(s1, off);
        s2 += __shfl_down(s2, off);
    }
    const int lane = tid & 63, wv = tid >> 6;
    if (lane == 0) { red[0][wv] = s1; red[1][wv] = s2; }
    __syncthreads();
    if (tid == 0) {
        a_s[n] = red[0][0] + red[0][1] + red[0][2];
        a_d[n] = red[1][0] + red[1][1] + red[1][2];
    }
}

// ---------------------------------------------------------------------------
// CSR build by dst (count -> scan -> scatter). Indices pre-clamped to [0,N).
// ---------------------------------------------------------------------------
__global__ void indeg_kernel(const int* __restrict__ eic, int* __restrict__ deg) {
    int e = blockIdx.x * 256 + threadIdx.x;
    if (e >= E_TOT) return;
    int dst = (e < E_EDGES) ? eic[E_EDGES + e] : (e - E_EDGES);
    atomicAdd(&deg[dst], 1);
}
__global__ __launch_bounds__(256) void scan_kernel(const int* __restrict__ deg, int* __restrict__ rowptr) {
    __shared__ int part[256];
    int t = threadIdx.x;
    int local[32];
    int s = 0;
#pragma unroll
    for (int i = 0; i < 32; ++i) { local[i] = deg[t * 32 + i]; s += local[i]; }
    part[t] = s;
    __syncthreads();
    for (int off = 1; off < 256; off <<= 1) {
        int v = (t >= off) ? part[t - off] : 0;
        __syncthreads();
        part[t] += v;
        __syncthreads();
    }
    int run = (t == 0) ? 0 : part[t - 1];
#pragma unroll
    for (int i = 0; i < 32; ++i) { rowptr[t * 32 + i] = run; run += local[i]; }
    if (t == 255) rowptr[N_NODES] = run;
}
__global__ void scatter_kernel(const int* __restrict__ eic, const int* __restrict__ rowptr,
                               int* __restrict__ fill, int* __restrict__ csr_src) {
    int e = blockIdx.x * 256 + threadIdx.x;
    if (e >= E_TOT) return;
    int src, dst;
    if (e < E_EDGES) { src = eic[e]; dst = eic[E_EDGES + e]; }
    else             { src = e - E_EDGES; dst = src; }
    int pos = rowptr[dst] + atomicAdd(&fill[dst], 1);
    csr_src[pos] = src;
}

// ---------------------------------------------------------------------------
// Layer-1 attention weight precompute (algebraic fusion), HEAD-MAJOR layout:
//   ws[h*768+d] = sum_c W1[d][h*768+c] * att_src1[h][c]. One wave per (d,h),
//   1536 blocks.
// ---------------------------------------------------------------------------
__global__ __launch_bounds__(256) void att1_wprep_kernel(
    const float* __restrict__ W1, const float* __restrict__ att_s,
    const float* __restrict__ att_d, float* __restrict__ ws, float* __restrict__ wd)
{
    int gid  = blockIdx.x * 4 + (threadIdx.x >> 6);   // 0..6143
    int lane = threadIdx.x & 63;
    int d = gid >> 3, h = gid & 7;
    const float* wp = W1 + (size_t)d * F1 + h * C_CH;
    const float* sp = att_s + h * C_CH;
    const float* dp = att_d + h * C_CH;
    float s1 = 0.f, s2 = 0.f;
#pragma unroll
    for (int j = 0; j < 3; ++j) {
        int o = j * 256 + lane * 4;
        f32x4 w  = *(const f32x4*)(wp + o);
        f32x4 sv = *(const f32x4*)(sp + o);
        f32x4 dv = *(const f32x4*)(dp + o);
#pragma unroll
        for (int k = 0; k < 4; ++k) { s1 += w[k] * sv[k]; s2 += w[k] * dv[k]; }
    }
#pragma unroll
    for (int off = 32; off > 0; off >>= 1) {
        s1 += __shfl_down(s1, off);
        s2 += __shfl_down(s2, off);
    }
    if (lane == 0) { ws[h * D_IN + d] = s1; wd[h * D_IN + d] = s2; }
}

// ---------------------------------------------------------------------------
// Layer-1 attention logits as a tiny GEMV: a_s1[n,h] = <xb[n,:], ws[h,:]>.
// One wave per node; fully coalesced f32x4 weight reads (head-major).
// ---------------------------------------------------------------------------
__global__ __launch_bounds__(256) void att1_gemv_kernel(
    const ushort_t* __restrict__ xb, const float* __restrict__ ws,
    const float* __restrict__ wd, float* __restrict__ a_s, float* __restrict__ a_d)
{
    int n    = blockIdx.x * 4 + (threadIdx.x >> 6);
    int lane = threadIdx.x & 63;
    const ushort_t* xp = xb + (size_t)n * D_IN;
    float s[8], d[8];
#pragma unroll
    for (int h = 0; h < 8; ++h) { s[h] = 0.f; d[h] = 0.f; }
#pragma unroll
    for (int j = 0; j < 3; ++j) {
        int d0 = j * 256 + lane * 4;
        ushort4v xv = *(const ushort4v*)(xp + d0);
        float xf0 = bf2f(xv[0]), xf1 = bf2f(xv[1]), xf2 = bf2f(xv[2]), xf3 = bf2f(xv[3]);
#pragma unroll
        for (int h = 0; h < 8; ++h) {
            f32x4 wv = *(const f32x4*)(ws + (size_t)h * D_IN + d0);
            f32x4 dv = *(const f32x4*)(wd + (size_t)h * D_IN + d0);
            s[h] += xf0 * wv[0] + xf1 * wv[1] + xf2 * wv[2] + xf3 * wv[3];
            d[h] += xf0 * dv[0] + xf1 * dv[1] + xf2 * dv[2] + xf3 * dv[3];
        }
    }
#pragma unroll
    for (int h = 0; h < 8; ++h) {
#pragma unroll
        for (int off = 32; off > 0; off >>= 1) {
            s[h] += __shfl_down(s[h], off);
            d[h] += __shfl_down(d[h], off);
        }
    }
    if (lane == 0) {
#pragma unroll
        for (int h = 0; h < 8; ++h) { a_s[n * 8 + h] = s[h]; a_d[n * 8 + h] = d[h]; }
    }
}

// ---------------------------------------------------------------------------
// Layer-1 aggregation IN X-SPACE (aggregate-then-project):
//   xagg[h][n][d] = sum_e alpha_e^h * xb[src_e][d]   (f32 accum -> bf16)
// One 192-thread block per node; thread owns 4 channels x 8 heads (32 f32).
// Each edge's x-row is read ONCE and reused for all 8 heads.
// ---------------------------------------------------------------------------
__global__ __launch_bounds__(192) void agg8x_kernel(
    const ushort_t* __restrict__ xb, const float* __restrict__ a_s, const float* __restrict__ a_d,
    const int* __restrict__ rowptr, const int* __restrict__ csr_src,
    ushort_t* __restrict__ xagg)
{
    const int n = blockIdx.x;
    const int tid = threadIdx.x;
    const int base = rowptr[n];
    const int deg  = rowptr[n + 1] - base;

    __shared__ float s_m[8], s_rd[8], s_adst[8];
    __shared__ int   s_src[64];
    __shared__ float s_w[64][8];

    if (tid < 8) {
        float adst = a_d[n * 8 + tid];
        float m = -1e30f;
        for (int e = 0; e < deg; ++e) {
            float scv = a_s[csr_src[base + e] * 8 + tid] + adst;
            scv = scv > 0.f ? scv : 0.2f * scv;
            m = fmaxf(m, scv);
        }
        float den = 0.f;
        for (int e = 0; e < deg; ++e) {
            float scv = a_s[csr_src[base + e] * 8 + tid] + adst;
            scv = scv > 0.f ? scv : 0.2f * scv;
            den += __expf(scv - m);
        }
        s_m[tid] = m; s_rd[tid] = 1.0f / (den + 1e-16f); s_adst[tid] = adst;
    }
    __syncthreads();

    float acc[8][4];
#pragma unroll
    for (int h = 0; h < 8; ++h)
#pragma unroll
        for (int i = 0; i < 4; ++i) acc[h][i] = 0.f;
    const int c0 = tid * 4;   // 192*4 = 768 channels

    for (int cs = 0; cs < deg; cs += 64) {
        int cnt = min(64, deg - cs);
        __syncthreads();
        for (int idx = tid; idx < cnt; idx += 192) s_src[idx] = csr_src[base + cs + idx];
        __syncthreads();
        for (int idx = tid; idx < cnt * 8; idx += 192) {
            int e = idx >> 3, hd = idx & 7;
            float scv = a_s[s_src[e] * 8 + hd] + s_adst[hd];
            scv = scv > 0.f ? scv : 0.2f * scv;
            s_w[e][hd] = __expf(scv - s_m[hd]) * s_rd[hd];
        }
        __syncthreads();
        for (int e = 0; e < cnt; ++e) {
            const ushort_t* xp = xb + (size_t)s_src[e] * D_IN + c0;
            ushort4v xv = *(const ushort4v*)(xp);
            float xf0 = bf2f(xv[0]), xf1 = bf2f(xv[1]), xf2 = bf2f(xv[2]), xf3 = bf2f(xv[3]);
#pragma unroll
            for (int h = 0; h < 8; ++h) {
                float w = s_w[e][h];
                acc[h][0] += w * xf0;
                acc[h][1] += w * xf1;
                acc[h][2] += w * xf2;
                acc[h][3] += w * xf3;
            }
        }
    }
#pragma unroll
    for (int h = 0; h < 8; ++h) {
        ushort_t o0 = f2bf(acc[h][0]), o1 = f2bf(acc[h][1]);
        ushort_t o2 = f2bf(acc[h][2]), o3 = f2bf(acc[h][3]);
        unsigned long long pk = (unsigned long long)o0 | ((unsigned long long)o1 << 16)
                              | ((unsigned long long)o2 << 32) | ((unsigned long long)o3 << 48);
        *(unsigned long long*)(xagg + ((size_t)h * N_NODES + n) * D_IN + c0) = pk;
    }
}

// ---------------------------------------------------------------------------
// Aggregation layer 2 (1 head, 768 ch): ONE WAVE per node (4 nodes/block).
// Lane owns 12 channels (3 x ushort4 8B loads); wave-parallel softmax stats;
// per-edge weight broadcast via shfl. Zero barriers.
// ---------------------------------------------------------------------------
__global__ __launch_bounds__(256) void agg1_kernel(
    const ushort_t* __restrict__ h, const float* __restrict__ a_s, const float* __restrict__ a_d,
    const int* __restrict__ rowptr, const int* __restrict__ csr_src,
    const float* __restrict__ bias, ushort_t* __restrict__ out)
{
    const int n    = blockIdx.x * 4 + (threadIdx.x >> 6);
    const int lane = threadIdx.x & 63;
    const int base = rowptr[n];
    const int deg  = rowptr[n + 1] - base;
    const float adst = a_d[n];

    float m = -1e30f;
    for (int cs = 0; cs < deg; cs += 64) {
        int e = cs + lane;
        if (e < deg) {
            float scv = a_s[csr_src[base + e]] + adst;
            scv = scv > 0.f ? scv : 0.2f * scv;
            m = fmaxf(m, scv);
        }
    }
#pragma unroll
    for (int off = 32; off > 0; off >>= 1) m = fmaxf(m, __shfl_xor(m, off));
    float den = 0.f;
    for (int cs = 0; cs < deg; cs += 64) {
        int e = cs + lane;
        if (e < deg) {
            float scv = a_s[csr_src[base + e]] + adst;
            scv = scv > 0.f ? scv : 0.2f * scv;
            den += __expf(scv - m);
        }
    }
#pragma unroll
    for (int off = 32; off > 0; off >>= 1) den += __shfl_xor(den, off);
    const float rd = 1.0f / (den + 1e-16f);

    const int c0 = lane * 12;
    float acc[12];
#pragma unroll
    for (int i = 0; i < 12; ++i) acc[i] = 0.f;

    for (int cs = 0; cs < deg; cs += 64) {
        int cnt = min(64, deg - cs);
        int e = cs + lane;
        int srcl = (e < deg) ? csr_src[base + e] : 0;
        float wv = 0.f;
        if (e < deg) {
            float scv = a_s[srcl] + adst;
            scv = scv > 0.f ? scv : 0.2f * scv;
            wv = __expf(scv - m) * rd;
        }
        for (int k = 0; k < cnt; ++k) {
            int src = __shfl(srcl, k);
            float w = __shfl(wv, k);
            const ushort_t* hp = h + (size_t)src * C_CH + c0;
            ushort4v v0 = *(const ushort4v*)(hp);
            ushort4v v1 = *(const ushort4v*)(hp + 4);
            ushort4v v2 = *(const ushort4v*)(hp + 8);
#pragma unroll
            for (int i = 0; i < 4; ++i) {
                acc[i]     += w * bf2f(v0[i]);
                acc[4 + i] += w * bf2f(v1[i]);
                acc[8 + i] += w * bf2f(v2[i]);
            }
        }
    }
#pragma unroll
    for (int p = 0; p < 3; ++p) {
        ushort_t o0 = f2bf(acc[p * 4 + 0] + bias[c0 + p * 4 + 0]);
        ushort_t o1 = f2bf(acc[p * 4 + 1] + bias[c0 + p * 4 + 1]);
        ushort_t o2 = f2bf(acc[p * 4 + 2] + bias[c0 + p * 4 + 2]);
        ushort_t o3 = f2bf(acc[p * 4 + 3] + bias[c0 + p * 4 + 3]);
        unsigned long long pk = (unsigned long long)o0 | ((unsigned long long)o1 << 16)
                              | ((unsigned long long)o2 << 32) | ((unsigned long long)o3 << 48);
        *(unsigned long long*)(out + (size_t)n * C_CH + c0 + p * 4) = pk;
    }
}

// ---------------------------------------------------------------------------
// Build fc input rows: Afc[m] = concat(out2[mask[m]], xb[mask[m]])  (bf16)
// ---------------------------------------------------------------------------
__global__ void gatherfc_kernel(const ushort_t* __restrict__ out2, const ushort_t* __restrict__ xb,
                                const int* __restrict__ maskc, ushort_t* __restrict__ Afc)
{
    int m = blockIdx.x, t = threadIdx.x;
    int mi = maskc[m];
    const ushort_t* p1 = out2 + (size_t)mi * 768;
    const ushort_t* p2 = xb   + (size_t)mi * 768;
    for (int c = t; c < 768; c += 256) {
        Afc[(size_t)m * 1536 + c]       = p1[c];
        Afc[(size_t)m * 1536 + 768 + c] = p2[c];
    }
}

// ---------------------------------------------------------------------------
// Classifier: out[m, 0:2] = fc_out[m] @ cls_w + cls_b (f32 out). One wave/row.
// ---------------------------------------------------------------------------
__global__ __launch_bounds__(256) void cls_kernel(
    const ushort_t* __restrict__ fc_out, const float* __restrict__ cls_w,
    const float* __restrict__ cls_b, float* __restrict__ out)
{
    int m = blockIdx.x * 4 + (threadIdx.x >> 6);
    int lane = threadIdx.x & 63;
    float a0 = 0.f, a1 = 0.f;
    const ushort_t* row = fc_out + (size_t)m * 768;
    for (int i = lane; i < 768; i += 64) {
        float v = bf2f(row[i]);
        a0 += v * cls_w[i * 2 + 0];
        a1 += v * cls_w[i * 2 + 1];
    }
#pragma unroll
    for (int off = 32; off > 0; off >>= 1) {
        a0 += __shfl_down(a0, off);
        a1 += __shfl_down(a1, off);
    }
    if (lane == 0) {
        out[m * 2 + 0] = a0 + cls_b[0];
        out[m * 2 + 1] = a1 + cls_b[1];
    }
}

extern "C" void kernel_launch(void* const* d_in, const int* in_sizes, int n_in,
                              void* d_out, int out_size, void* d_ws, size_t ws_size,
                              hipStream_t stream)
{
    const float* x        = (const float*)d_in[0];
    const void*  ei_raw   = d_in[1];
    const void*  mask_raw = d_in[2];
    const float* W1       = (const float*)d_in[3];
    const float* att_src1 = (const float*)d_in[4];
    const float* att_dst1 = (const float*)d_in[5];
    const float* b1       = (const float*)d_in[6];
    const float* W2       = (const float*)d_in[7];
    const float* att_src2 = (const float*)d_in[8];
    const float* att_dst2 = (const float*)d_in[9];
    const float* b2       = (const float*)d_in[10];
    const float* fc_w     = (const float*)d_in[11];
    const float* fc_b     = (const float*)d_in[12];
    const float* cls_w    = (const float*)d_in[13];
    const float* cls_b    = (const float*)d_in[14];
    float* out = (float*)d_out;

    // ---- workspace layout ----
    char* ws = (char*)d_ws;
    size_t off = 0;
    auto alloc = [&](size_t bytes) { char* p = ws + off; off = (off + bytes + 255) & ~(size_t)255; return p; };
    int*   flags  = (int*)alloc(2 * 4);
    int*   eic    = (int*)alloc((size_t)2 * E_EDGES * 4);
    int*   maskc  = (int*)alloc((size_t)M_MASK * 4);
    int*   deg    = (int*)alloc(N_NODES * 4);
    int*   fill   = (int*)alloc(N_NODES * 4);
    int*   rowptr = (int*)alloc((N_NODES + 1) * 4);
    int*   csr    = (int*)alloc(E_TOT * 4);
    float* a_s1   = (float*)alloc((size_t)N_NODES * 8 * 4);
    float* a_d1   = (float*)alloc((size_t)N_NODES * 8 * 4);
    float* a_s2   = (float*)alloc((size_t)N_NODES * 4);
    float* a_d2   = (float*)alloc((size_t)N_NODES * 4);
    float* ws1    = (float*)alloc((size_t)D_IN * 8 * 4);   // att1 algebraic weights (head-major)
    float* wd1    = (float*)alloc((size_t)D_IN * 8 * 4);
    ushort_t* W1t  = (ushort_t*)alloc((size_t)D_IN * F1 * 2);
    ushort_t* W2t  = (ushort_t*)alloc((size_t)F1 * C_CH * 2);
    ushort_t* fcwt = (ushort_t*)alloc((size_t)1536 * 768 * 2);
    ushort_t* xb   = (ushort_t*)alloc((size_t)N_NODES * D_IN * 2);
    char* region1 = alloc((size_t)N_NODES * F1 * 2);   // xagg, later h2/Afc/fcout/partials
    char* region2 = alloc((size_t)N_NODES * F1 * 2);   // out1, later out2
    ushort_t* xagg  = (ushort_t*)region1;                   // [8][8192][768] bf16 = 100.7MB
    ushort_t* h2    = (ushort_t*)region1;                   // after xagg dead (12.6MB)
    ushort_t* Afc   = (ushort_t*)(region1 + (16u << 20));   // 6.3MB @ 16MiB
    ushort_t* fcout = (ushort_t*)(region1 + (32u << 20));   // 3.1MB @ 32MiB
    ushort_t* part  = (ushort_t*)(region1 + (48u << 20));   // 4x12.6MB bf16 split-K partials @ 48MiB (xagg dead)
    ushort_t* out1  = (ushort_t*)region2;
    ushort_t* out2  = (ushort_t*)region2;                   // after out1 dead

    // ---- index conversion + CSR build ----
    init_kernel<<<N_NODES / 256, 256, 0, stream>>>(deg, fill, flags);
    detect2_kernel<<<(E_EDGES + M_MASK / 2 + 255) / 256, 256, 0, stream>>>(
        (const int*)ei_raw, (const int*)mask_raw, flags);
    convert2_kernel<<<(2 * E_EDGES + M_MASK + 255) / 256, 256, 0, stream>>>(
        ei_raw, mask_raw, flags, eic, maskc);
    indeg_kernel<<<E_TOT / 256, 256, 0, stream>>>(eic, deg);
    scan_kernel<<<1, 256, 0, stream>>>(deg, rowptr);
    scatter_kernel<<<E_TOT / 256, 256, 0, stream>>>(eic, rowptr, fill, csr);

    // ---- converts + att1 algebraic path (all BEFORE the big GEMM) ----
    cvt_bf16_kernel<<<(N_NODES * D_IN / 4 + 255) / 256, 256, 0, stream>>>(x, xb, N_NODES * D_IN / 4);
    att1_wprep_kernel<<<(D_IN * 8) / 4, 256, 0, stream>>>(W1, att_src1, att_dst1, ws1, wd1);
    att1_gemv_kernel<<<N_NODES / 4, 256, 0, stream>>>(xb, ws1, wd1, a_s1, a_d1);
    transpose_cvt_kernel<<<dim3(F1 / 32, D_IN / 32), 256, 0, stream>>>(W1, W1t, D_IN, F1);
    transpose_cvt_kernel<<<dim3(C_CH / 32, F1 / 32), 256, 0, stream>>>(W2, W2t, F1, C_CH);
    transpose_cvt_kernel<<<dim3(768 / 32, 1536 / 32), 256, 0, stream>>>(fc_w, fcwt, 1536, 768);

    // ---- layer 1 (aggregate-then-project): no h1 materialization ----
    agg8x_kernel<<<N_NODES, 192, 0, stream>>>(xb, a_s1, a_d1, rowptr, csr, xagg);
    gemm_bd_kernel<<<NBX_BD * NBY_BD * 8, 256, 0, stream>>>(xagg, W1t, out1, b1, N_NODES, D_IN);

    // ---- layer 2 ----  (xagg dead: region1 reused for h2 + split-K partials)
    gemm_bt_splitk_kernel<<<NBX2 * NBY2 * NSPLIT, 256, 0, stream>>>(out1, W2t, part, N_NODES, C_CH, F1);
    splitk_reduce_att_kernel<<<N_NODES, 192, 0, stream>>>(
        part, h2, att_src2, att_dst2, a_s2, a_d2);
    agg1_kernel<<<N_NODES / 4, 256, 0, stream>>>(h2, a_s2, a_d2, rowptr, csr, b2, out2);  // out1 dead

    // ---- head ----
    gatherfc_kernel<<<M_MASK, 256, 0, stream>>>(out2, xb, maskc, Afc);
    gemm_bt_kernel<<<dim3(768 / 128, M_MASK / 128), 256, 0, stream>>>(Afc, fcwt, fcout, fc_b, M_MASK, 768, 1536);
    cls_kernel<<<M_MASK / 4, 256, 0, stream>>>(fcout, cls_w, cls_b, out);
}

// Round 15
// 467.770 us; speedup vs baseline: 1.7662x; 1.7662x over previous
//
#include <hip/hip_runtime.h>

typedef unsigned short ushort_t;
typedef __attribute__((ext_vector_type(8))) __bf16 bf16x8;
typedef __attribute__((ext_vector_type(8))) unsigned short ushort8;
typedef __attribute__((ext_vector_type(4))) unsigned short ushort4v;
typedef __attribute__((ext_vector_type(4))) float f32x4;

#define N_NODES 8192
#define NODE_MASK 8191
#define E_EDGES 32768
#define E_TOT   40960   /* E + N self loops */
#define M_MASK  2048
#define D_IN    768
#define C_CH    768
#define F1      6144    /* 8 heads * 768 */

typedef __attribute__((address_space(1))) const void* gas_ptr;
typedef __attribute__((address_space(3))) void* las_ptr;

__device__ __forceinline__ float bf2f(ushort_t u) {
    union { unsigned int i; float f; } v; v.i = ((unsigned int)u) << 16; return v.f;
}
__device__ __forceinline__ ushort_t f2bf(float f) {
    union { float f; unsigned int i; } v; v.f = f;
    unsigned int r = v.i + 0x7fffu + ((v.i >> 16) & 1u);
    return (ushort_t)(r >> 16);
}

// ---------------------------------------------------------------------------
// int64-vs-int32 detection + conversion of index arrays (clamped to [0,N)).
// SEPARATE kernels per array (R14's merged detect2 put the atomicOr behind a
// divergent address select -> per-lane serialized device atomics, 385 us).
// detect uses __any() -> ONE atomicOr per wave, robust to compiler behavior.
// ---------------------------------------------------------------------------
__global__ void init_kernel(int* deg, int* fill, int* flags) {
    int i = blockIdx.x * 256 + threadIdx.x;
    if (i < N_NODES) { deg[i] = 0; fill[i] = 0; }
    if (i < 2) flags[i] = 0;
}
__global__ void detect_kernel(const int* __restrict__ raw, int nhalf, int* __restrict__ flag) {
    int i = blockIdx.x * 256 + threadIdx.x;
    bool nz = (i < nhalf) && (raw[2 * i + 1] != 0);
    if (__any(nz) && (threadIdx.x & 63) == 0) atomicOr(flag, 1);
}
__global__ void convert_idx_kernel(const void* __restrict__ raw, int n,
                                   const int* __restrict__ flag, int* __restrict__ out) {
    int i = blockIdx.x * 256 + threadIdx.x;
    if (i >= n) return;
    int v = (*flag) ? ((const int*)raw)[i] : (int)((const long long*)raw)[i];
    out[i] = v & NODE_MASK;
}

// ---------------------------------------------------------------------------
// f32 -> bf16 elementwise convert (vectorized)
// ---------------------------------------------------------------------------
__global__ void cvt_bf16_kernel(const float* __restrict__ in, ushort_t* __restrict__ out, int n4) {
    int i = blockIdx.x * 256 + threadIdx.x;
    if (i >= n4) return;
    f32x4 v = *(const f32x4*)(in + i * 4);
    ushort_t o0 = f2bf(v[0]), o1 = f2bf(v[1]), o2 = f2bf(v[2]), o3 = f2bf(v[3]);
    unsigned long long pk = (unsigned long long)o0 | ((unsigned long long)o1 << 16)
                          | ((unsigned long long)o2 << 32) | ((unsigned long long)o3 << 48);
    *(unsigned long long*)(out + i * 4) = pk;
}

// ---------------------------------------------------------------------------
// f32 -> bf16 transpose: out[c][r] = (bf16)in[r][c]; in is R x Ccols f32.
// ---------------------------------------------------------------------------
__global__ __launch_bounds__(256) void transpose_cvt_kernel(
    const float* __restrict__ in, ushort_t* __restrict__ out, int R, int Ccols)
{
    __shared__ ushort_t tile[32][33];
    int tx = threadIdx.x & 31, ty = threadIdx.x >> 5;
    int x  = blockIdx.x * 32 + tx;
    int y0 = blockIdx.y * 32;
#pragma unroll
    for (int i = 0; i < 4; ++i)
        tile[ty + i * 8][tx] = f2bf(in[(size_t)(y0 + ty + i * 8) * Ccols + x]);
    __syncthreads();
#pragma unroll
    for (int i = 0; i < 4; ++i)
        out[(size_t)(blockIdx.x * 32 + ty + i * 8) * R + y0 + tx] = tile[tx][ty + i * 8];
}

// ---------------------------------------------------------------------------
// bf16 MFMA GEMM:  C[M,N] = A[M,K] * Bt[N,K]^T  (+ optional f32 bias[N]) -> bf16
// 128x128 tile, BK=64, 256 threads (m97 structure, 84 VGPR). Used for head GEMM.
// ---------------------------------------------------------------------------
__global__ __launch_bounds__(256) void gemm_bt_kernel(
    const ushort_t* __restrict__ A, const ushort_t* __restrict__ Bt,
    ushort_t* __restrict__ C, const float* __restrict__ bias,
    int M, int N, int K)
{
    __shared__ ushort_t lsA[128 * 64];
    __shared__ ushort_t lsB[128 * 64];

    const int tid  = threadIdx.x;
    const int lane = tid & 63;
    const int wave = tid >> 6;
    const int wm = wave >> 1, wn = wave & 1;
    const int bx = blockIdx.x, by = blockIdx.y;

    const f32x4 zero = {0.f, 0.f, 0.f, 0.f};
    f32x4 acc[4][4];
#pragma unroll
    for (int i = 0; i < 4; ++i)
#pragma unroll
        for (int j = 0; j < 4; ++j) acc[i][j] = zero;

    const int l8 = lane >> 3;   // row within 8-row group
    const int c8 = lane & 7;    // 16B chunk slot
    const int q  = lane >> 4;   // quad
    const int rl = lane & 15;

    for (int kt = 0; kt < K; kt += 64) {
        __syncthreads();   // previous tile fully consumed
#pragma unroll
        for (int i = 0; i < 4; ++i) {
            int rbase = wave * 32 + i * 8;      // wave-uniform
            int row   = rbase + l8;             // per-lane
            int gch   = c8 ^ (row & 7);         // swizzle on source
            const ushort_t* gA = A  + (size_t)(by * 128 + row) * K + kt + gch * 8;
            const ushort_t* gB = Bt + (size_t)(bx * 128 + row) * K + kt + gch * 8;
            __builtin_amdgcn_global_load_lds((gas_ptr)gA, (las_ptr)(lsA + rbase * 64), 16, 0, 0);
            __builtin_amdgcn_global_load_lds((gas_ptr)gB, (las_ptr)(lsB + rbase * 64), 16, 0, 0);
        }
        __syncthreads();   // vmcnt drained by barrier semantics
#pragma unroll
        for (int s = 0; s < 2; ++s) {
            bf16x8 af[4], bfv[4];
#pragma unroll
            for (int i = 0; i < 4; ++i) {
                int Ra = wm * 64 + i * 16 + rl;
                af[i]  = *(const bf16x8*)(lsA + Ra * 64 + (((s * 4 + q) ^ (Ra & 7)) * 8));
                int Rb = wn * 64 + i * 16 + rl;
                bfv[i] = *(const bf16x8*)(lsB + Rb * 64 + (((s * 4 + q) ^ (Rb & 7)) * 8));
            }
#pragma unroll
            for (int i = 0; i < 4; ++i)
#pragma unroll
                for (int j = 0; j < 4; ++j)
                    acc[i][j] = __builtin_amdgcn_mfma_f32_16x16x32_bf16(af[i], bfv[j], acc[i][j], 0, 0, 0);
        }
    }
    // epilogue: C/D layout col=lane&15, row=quad*4+reg (m89-verified)
#pragma unroll
    for (int j = 0; j < 4; ++j) {
        int col = bx * 128 + wn * 64 + j * 16 + rl;
        float bv = bias ? bias[col] : 0.0f;
#pragma unroll
        for (int i = 0; i < 4; ++i) {
#pragma unroll
            for (int t = 0; t < 4; ++t) {
                int row = by * 128 + wm * 64 + i * 16 + q * 4 + t;
                C[(size_t)row * N + col] = f2bf(acc[i][j][t] + bv);
            }
        }
    }
}

// ---------------------------------------------------------------------------
// Per-head block-diagonal GEMM for layer 1 (aggregate-then-project algebra):
//   out1[n, h*768+c] = ELU( b1[h*768+c] + xagg_h[n,:] @ W1t[h*768+c,:] )
// Linear grid of 3072 blocks with XCD-aware panel-grouping decode; head==xcd
// so each XCD's W1t panel + xagg slice stay L2-resident (FETCH 314->66MB).
// bias+ELU fused in-place on acc.
// ---------------------------------------------------------------------------
#define NBX_BD 6     /* 768/128 */
#define NBY_BD 64    /* 8192/128 */

__global__ __launch_bounds__(256) void gemm_bd_kernel(
    const ushort_t* __restrict__ A0, const ushort_t* __restrict__ Bt0,
    ushort_t* __restrict__ C, const float* __restrict__ bias,
    int M, int K)
{
    __shared__ ushort_t lsA[128 * 64];
    __shared__ ushort_t lsB[128 * 64];

    const int tid  = threadIdx.x;
    const int lane = tid & 63;
    const int wave = tid >> 6;
    const int wm = wave >> 1, wn = wave & 1;

    // XCD-aware bijective decode (3072 blocks, 8 XCDs, 64 panel-groups/XCD)
    const int d    = blockIdx.x;
    const int xcd  = d & 7;
    const int slot = d >> 3;                 // 0..383
    const int bx   = slot % NBX_BD;          // 0..5
    const int grp  = xcd * 64 + slot / NBX_BD;   // 0..511
    const int by   = grp & (NBY_BD - 1);
    const int head = grp >> 6;               // == xcd

    const ushort_t* A  = A0  + (size_t)head * M * K;
    const ushort_t* Bt = Bt0 + (size_t)head * C_CH * K;

    const f32x4 zero = {0.f, 0.f, 0.f, 0.f};
    f32x4 acc[4][4];
#pragma unroll
    for (int i = 0; i < 4; ++i)
#pragma unroll
        for (int j = 0; j < 4; ++j) acc[i][j] = zero;

    const int l8 = lane >> 3;
    const int c8 = lane & 7;
    const int q  = lane >> 4;
    const int rl = lane & 15;

    for (int kt = 0; kt < K; kt += 64) {
        __syncthreads();
#pragma unroll
        for (int i = 0; i < 4; ++i) {
            int rbase = wave * 32 + i * 8;
            int row   = rbase + l8;
            int gch   = c8 ^ (row & 7);
            const ushort_t* gA = A  + (size_t)(by * 128 + row) * K + kt + gch * 8;
            const ushort_t* gB = Bt + (size_t)(bx * 128 + row) * K + kt + gch * 8;
            __builtin_amdgcn_global_load_lds((gas_ptr)gA, (las_ptr)(lsA + rbase * 64), 16, 0, 0);
            __builtin_amdgcn_global_load_lds((gas_ptr)gB, (las_ptr)(lsB + rbase * 64), 16, 0, 0);
        }
        __syncthreads();
#pragma unroll
        for (int s = 0; s < 2; ++s) {
            bf16x8 af[4], bfv[4];
#pragma unroll
            for (int i = 0; i < 4; ++i) {
                int Ra = wm * 64 + i * 16 + rl;
                af[i]  = *(const bf16x8*)(lsA + Ra * 64 + (((s * 4 + q) ^ (Ra & 7)) * 8));
                int Rb = wn * 64 + i * 16 + rl;
                bfv[i] = *(const bf16x8*)(lsB + Rb * 64 + (((s * 4 + q) ^ (Rb & 7)) * 8));
            }
#pragma unroll
            for (int i = 0; i < 4; ++i)
#pragma unroll
                for (int j = 0; j < 4; ++j)
                    acc[i][j] = __builtin_amdgcn_mfma_f32_16x16x32_bf16(af[i], bfv[j], acc[i][j], 0, 0, 0);
        }
    }
    // epilogue: bias + ELU fused, store into the full 6144-wide out1
#pragma unroll
    for (int j = 0; j < 4; ++j) {
        int colf = head * C_CH + bx * 128 + wn * 64 + j * 16 + rl;
        float bv = bias[colf];
#pragma unroll
        for (int i = 0; i < 4; ++i) {
#pragma unroll
            for (int t = 0; t < 4; ++t) {
                int row = by * 128 + wm * 64 + i * 16 + q * 4 + t;
                float v = acc[i][j][t] + bv;
                v = v > 0.f ? v : (__expf(v) - 1.0f);   // ELU
                C[(size_t)row * F1 + colf] = f2bf(v);
            }
        }
    }
}

// ---------------------------------------------------------------------------
// Split-K variant for the N=768 layer-2 GEMM, NSPLIT=4, bf16 partials.
// 1536 blocks = 6/CU dispatched for latency hiding; bf16 partials keep
// total partial traffic equal to the old f32 x2 scheme. XCD decode: all 6
// bx-blocks of one A-panel on one XCD.
// ---------------------------------------------------------------------------
#define NBX2 6      /* N=768 / 128 */
#define NBY2 64     /* M=8192 / 128 */
#define NSPLIT 4

__global__ __launch_bounds__(256) void gemm_bt_splitk_kernel(
    const ushort_t* __restrict__ A, const ushort_t* __restrict__ Bt,
    ushort_t* __restrict__ Cpart, int M, int N, int K)
{
    __shared__ ushort_t lsA[128 * 64];
    __shared__ ushort_t lsB[128 * 64];

    const int tid  = threadIdx.x;
    const int lane = tid & 63;
    const int wave = tid >> 6;
    const int wm = wave >> 1, wn = wave & 1;

    // XCD-aware bijective decode (1536 blocks, 8 XCDs, 32 panel-groups/XCD)
    const int d    = blockIdx.x;
    const int xcd  = d & 7;
    const int slot = d >> 3;                  // 0..191
    const int bx   = slot % NBX2;             // 0..5
    const int grp  = xcd * 32 + slot / NBX2;  // 0..255
    const int by   = grp & (NBY2 - 1);        // 0..63
    const int bz   = grp >> 6;                // 0..3

    const int kh  = K >> 2;
    const int kt0 = bz * kh;
    ushort_t* __restrict__ Cp = Cpart + (size_t)bz * M * N;

    const f32x4 zero = {0.f, 0.f, 0.f, 0.f};
    f32x4 acc[4][4];
#pragma unroll
    for (int i = 0; i < 4; ++i)
#pragma unroll
        for (int j = 0; j < 4; ++j) acc[i][j] = zero;

    const int l8 = lane >> 3;
    const int c8 = lane & 7;
    const int q  = lane >> 4;
    const int rl = lane & 15;

    for (int kt = kt0; kt < kt0 + kh; kt += 64) {
        __syncthreads();
#pragma unroll
        for (int i = 0; i < 4; ++i) {
            int rbase = wave * 32 + i * 8;
            int row   = rbase + l8;
            int gch   = c8 ^ (row & 7);
            const ushort_t* gA = A  + (size_t)(by * 128 + row) * K + kt + gch * 8;
            const ushort_t* gB = Bt + (size_t)(bx * 128 + row) * K + kt + gch * 8;
            __builtin_amdgcn_global_load_lds((gas_ptr)gA, (las_ptr)(lsA + rbase * 64), 16, 0, 0);
            __builtin_amdgcn_global_load_lds((gas_ptr)gB, (las_ptr)(lsB + rbase * 64), 16, 0, 0);
        }
        __syncthreads();
#pragma unroll
        for (int s = 0; s < 2; ++s) {
            bf16x8 af[4], bfv[4];
#pragma unroll
            for (int i = 0; i < 4; ++i) {
                int Ra = wm * 64 + i * 16 + rl;
                af[i]  = *(const bf16x8*)(lsA + Ra * 64 + (((s * 4 + q) ^ (Ra & 7)) * 8));
                int Rb = wn * 64 + i * 16 + rl;
                bfv[i] = *(const bf16x8*)(lsB + Rb * 64 + (((s * 4 + q) ^ (Rb & 7)) * 8));
            }
#pragma unroll
            for (int i = 0; i < 4; ++i)
#pragma unroll
                for (int j = 0; j < 4; ++j)
                    acc[i][j] = __builtin_amdgcn_mfma_f32_16x16x32_bf16(af[i], bfv[j], acc[i][j], 0, 0, 0);
        }
    }
#pragma unroll
    for (int j = 0; j < 4; ++j) {
        int col = bx * 128 + wn * 64 + j * 16 + rl;
#pragma unroll
        for (int i = 0; i < 4; ++i) {
#pragma unroll
            for (int t = 0; t < 4; ++t) {
                int row = by * 128 + wm * 64 + i * 16 + q * 4 + t;
                Cp[(size_t)row * N + col] = f2bf(acc[i][j][t]);
            }
        }
    }
}

// ---------------------------------------------------------------------------
// Split-K reduce (4 bf16 partials) + fused layer-2 attention logits.
// One 192-thread block per node: h2[n] = sum_k Pk[n] -> bf16, and
// a_s2/a_d2 via block reduce. No atomics.
// ---------------------------------------------------------------------------
__global__ __launch_bounds__(192) void splitk_reduce_att_kernel(
    const ushort_t* __restrict__ P, ushort_t* __restrict__ out,
    const float* __restrict__ as2, const float* __restrict__ ad2,
    float* __restrict__ a_s, float* __restrict__ a_d)
{
    const int n = blockIdx.x, tid = threadIdx.x;
    const int c0 = tid * 4;
    float v[4] = {0.f, 0.f, 0.f, 0.f};
#pragma unroll
    for (int k = 0; k < NSPLIT; ++k) {
        ushort4v p = *(const ushort4v*)(P + ((size_t)k * N_NODES + n) * C_CH + c0);
#pragma unroll
        for (int t = 0; t < 4; ++t) v[t] += bf2f(p[t]);
    }
    f32x4 ws = *(const f32x4*)(as2 + c0);
    f32x4 wd = *(const f32x4*)(ad2 + c0);
    float s1 = 0.f, s2 = 0.f;
    ushort_t o[4];
#pragma unroll
    for (int t = 0; t < 4; ++t) {
        o[t] = f2bf(v[t]);
        s1 += v[t] * ws[t];
        s2 += v[t] * wd[t];
    }
    unsigned long long pk = (unsigned long long)o[0] | ((unsigned long long)o[1] << 16)
                          | ((unsigned long long)o[2] << 32) | ((unsigned long long)o[3] << 48);
    *(unsigned long long*)(out + (size_t)n * C_CH + c0) = pk;

    __shared__ float red[2][3];
#pragma unroll
    for (int off = 32; off > 0; off >>= 1) {
        s1 += __shfl_down(s1, off);
        s2 += __shfl_down(s2, off);
    }
    const int lane = tid & 63, wv = tid >> 6;
    if (lane == 0) { red[0][wv] = s1; red[1][wv] = s2; }
    __syncthreads();
    if (tid == 0) {
        a_s[n] = red[0][0] + red[0][1] + red[0][2];
        a_d[n] = red[1][0] + red[1][1] + red[1][2];
    }
}

// ---------------------------------------------------------------------------
// CSR build by dst (count -> scan -> scatter). Indices pre-clamped to [0,N).
// ---------------------------------------------------------------------------
__global__ void indeg_kernel(const int* __restrict__ eic, int* __restrict__ deg) {
    int e = blockIdx.x * 256 + threadIdx.x;
    if (e >= E_TOT) return;
    int dst = (e < E_EDGES) ? eic[E_EDGES + e] : (e - E_EDGES);
    atomicAdd(&deg[dst], 1);
}
__global__ __launch_bounds__(256) void scan_kernel(const int* __restrict__ deg, int* __restrict__ rowptr) {
    __shared__ int part[256];
    int t = threadIdx.x;
    int local[32];
    int s = 0;
#pragma unroll
    for (int i = 0; i < 32; ++i) { local[i] = deg[t * 32 + i]; s += local[i]; }
    part[t] = s;
    __syncthreads();
    for (int off = 1; off < 256; off <<= 1) {
        int v = (t >= off) ? part[t - off] : 0;
        __syncthreads();
        part[t] += v;
        __syncthreads();
    }
    int run = (t == 0) ? 0 : part[t - 1];
#pragma unroll
    for (int i = 0; i < 32; ++i) { rowptr[t * 32 + i] = run; run += local[i]; }
    if (t == 255) rowptr[N_NODES] = run;
}
__global__ void scatter_kernel(const int* __restrict__ eic, const int* __restrict__ rowptr,
                               int* __restrict__ fill, int* __restrict__ csr_src) {
    int e = blockIdx.x * 256 + threadIdx.x;
    if (e >= E_TOT) return;
    int src, dst;
    if (e < E_EDGES) { src = eic[e]; dst = eic[E_EDGES + e]; }
    else             { src = e - E_EDGES; dst = src; }
    int pos = rowptr[dst] + atomicAdd(&fill[dst], 1);
    csr_src[pos] = src;
}

// ---------------------------------------------------------------------------
// Layer-1 attention weight precompute (algebraic fusion), HEAD-MAJOR layout:
//   ws[h*768+d] = sum_c W1[d][h*768+c] * att_src1[h][c]. One wave per (d,h),
//   1536 blocks.
// ---------------------------------------------------------------------------
__global__ __launch_bounds__(256) void att1_wprep_kernel(
    const float* __restrict__ W1, const float* __restrict__ att_s,
    const float* __restrict__ att_d, float* __restrict__ ws, float* __restrict__ wd)
{
    int gid  = blockIdx.x * 4 + (threadIdx.x >> 6);   // 0..6143
    int lane = threadIdx.x & 63;
    int d = gid >> 3, h = gid & 7;
    const float* wp = W1 + (size_t)d * F1 + h * C_CH;
    const float* sp = att_s + h * C_CH;
    const float* dp = att_d + h * C_CH;
    float s1 = 0.f, s2 = 0.f;
#pragma unroll
    for (int j = 0; j < 3; ++j) {
        int o = j * 256 + lane * 4;
        f32x4 w  = *(const f32x4*)(wp + o);
        f32x4 sv = *(const f32x4*)(sp + o);
        f32x4 dv = *(const f32x4*)(dp + o);
#pragma unroll
        for (int k = 0; k < 4; ++k) { s1 += w[k] * sv[k]; s2 += w[k] * dv[k]; }
    }
#pragma unroll
    for (int off = 32; off > 0; off >>= 1) {
        s1 += __shfl_down(s1, off);
        s2 += __shfl_down(s2, off);
    }
    if (lane == 0) { ws[h * D_IN + d] = s1; wd[h * D_IN + d] = s2; }
}

// ---------------------------------------------------------------------------
// Layer-1 attention logits as a tiny GEMV: a_s1[n,h] = <xb[n,:], ws[h,:]>.
// One wave per node; fully coalesced f32x4 weight reads (head-major).
// ---------------------------------------------------------------------------
__global__ __launch_bounds__(256) void att1_gemv_kernel(
    const ushort_t* __restrict__ xb, const float* __restrict__ ws,
    const float* __restrict__ wd, float* __restrict__ a_s, float* __restrict__ a_d)
{
    int n    = blockIdx.x * 4 + (threadIdx.x >> 6);
    int lane = threadIdx.x & 63;
    const ushort_t* xp = xb + (size_t)n * D_IN;
    float s[8], d[8];
#pragma unroll
    for (int h = 0; h < 8; ++h) { s[h] = 0.f; d[h] = 0.f; }
#pragma unroll
    for (int j = 0; j < 3; ++j) {
        int d0 = j * 256 + lane * 4;
        ushort4v xv = *(const ushort4v*)(xp + d0);
        float xf0 = bf2f(xv[0]), xf1 = bf2f(xv[1]), xf2 = bf2f(xv[2]), xf3 = bf2f(xv[3]);
#pragma unroll
        for (int h = 0; h < 8; ++h) {
            f32x4 wv = *(const f32x4*)(ws + (size_t)h * D_IN + d0);
            f32x4 dv = *(const f32x4*)(wd + (size_t)h * D_IN + d0);
            s[h] += xf0 * wv[0] + xf1 * wv[1] + xf2 * wv[2] + xf3 * wv[3];
            d[h] += xf0 * dv[0] + xf1 * dv[1] + xf2 * dv[2] + xf3 * dv[3];
        }
    }
#pragma unroll
    for (int h = 0; h < 8; ++h) {
#pragma unroll
        for (int off = 32; off > 0; off >>= 1) {
            s[h] += __shfl_down(s[h], off);
            d[h] += __shfl_down(d[h], off);
        }
    }
    if (lane == 0) {
#pragma unroll
        for (int h = 0; h < 8; ++h) { a_s[n * 8 + h] = s[h]; a_d[n * 8 + h] = d[h]; }
    }
}

// ---------------------------------------------------------------------------
// Layer-1 aggregation IN X-SPACE (aggregate-then-project):
//   xagg[h][n][d] = sum_e alpha_e^h * xb[src_e][d]   (f32 accum -> bf16)
// One 192-thread block per node; thread owns 4 channels x 8 heads (32 f32).
// Each edge's x-row is read ONCE and reused for all 8 heads.
// ---------------------------------------------------------------------------
__global__ __launch_bounds__(192) void agg8x_kernel(
    const ushort_t* __restrict__ xb, const float* __restrict__ a_s, const float* __restrict__ a_d,
    const int* __restrict__ rowptr, const int* __restrict__ csr_src,
    ushort_t* __restrict__ xagg)
{
    const int n = blockIdx.x;
    const int tid = threadIdx.x;
    const int base = rowptr[n];
    const int deg  = rowptr[n + 1] - base;

    __shared__ float s_m[8], s_rd[8], s_adst[8];
    __shared__ int   s_src[64];
    __shared__ float s_w[64][8];

    if (tid < 8) {
        float adst = a_d[n * 8 + tid];
        float m = -1e30f;
        for (int e = 0; e < deg; ++e) {
            float scv = a_s[csr_src[base + e] * 8 + tid] + adst;
            scv = scv > 0.f ? scv : 0.2f * scv;
            m = fmaxf(m, scv);
        }
        float den = 0.f;
        for (int e = 0; e < deg; ++e) {
            float scv = a_s[csr_src[base + e] * 8 + tid] + adst;
            scv = scv > 0.f ? scv : 0.2f * scv;
            den += __expf(scv - m);
        }
        s_m[tid] = m; s_rd[tid] = 1.0f / (den + 1e-16f); s_adst[tid] = adst;
    }
    __syncthreads();

    float acc[8][4];
#pragma unroll
    for (int h = 0; h < 8; ++h)
#pragma unroll
        for (int i = 0; i < 4; ++i) acc[h][i] = 0.f;
    const int c0 = tid * 4;   // 192*4 = 768 channels

    for (int cs = 0; cs < deg; cs += 64) {
        int cnt = min(64, deg - cs);
        __syncthreads();
        for (int idx = tid; idx < cnt; idx += 192) s_src[idx] = csr_src[base + cs + idx];
        __syncthreads();
        for (int idx = tid; idx < cnt * 8; idx += 192) {
            int e = idx >> 3, hd = idx & 7;
            float scv = a_s[s_src[e] * 8 + hd] + s_adst[hd];
            scv = scv > 0.f ? scv : 0.2f * scv;
            s_w[e][hd] = __expf(scv - s_m[hd]) * s_rd[hd];
        }
        __syncthreads();
        for (int e = 0; e < cnt; ++e) {
            const ushort_t* xp = xb + (size_t)s_src[e] * D_IN + c0;
            ushort4v xv = *(const ushort4v*)(xp);
            float xf0 = bf2f(xv[0]), xf1 = bf2f(xv[1]), xf2 = bf2f(xv[2]), xf3 = bf2f(xv[3]);
#pragma unroll
            for (int h = 0; h < 8; ++h) {
                float w = s_w[e][h];
                acc[h][0] += w * xf0;
                acc[h][1] += w * xf1;
                acc[h][2] += w * xf2;
                acc[h][3] += w * xf3;
            }
        }
    }
#pragma unroll
    for (int h = 0; h < 8; ++h) {
        ushort_t o0 = f2bf(acc[h][0]), o1 = f2bf(acc[h][1]);
        ushort_t o2 = f2bf(acc[h][2]), o3 = f2bf(acc[h][3]);
        unsigned long long pk = (unsigned long long)o0 | ((unsigned long long)o1 << 16)
                              | ((unsigned long long)o2 << 32) | ((unsigned long long)o3 << 48);
        *(unsigned long long*)(xagg + ((size_t)h * N_NODES + n) * D_IN + c0) = pk;
    }
}

// ---------------------------------------------------------------------------
// Aggregation layer 2 (1 head, 768 ch): ONE WAVE per node (4 nodes/block).
// Lane owns 12 channels (3 x ushort4 8B loads); wave-parallel softmax stats;
// per-edge weight broadcast via shfl. Zero barriers.
// ---------------------------------------------------------------------------
__global__ __launch_bounds__(256) void agg1_kernel(
    const ushort_t* __restrict__ h, const float* __restrict__ a_s, const float* __restrict__ a_d,
    const int* __restrict__ rowptr, const int* __restrict__ csr_src,
    const float* __restrict__ bias, ushort_t* __restrict__ out)
{
    const int n    = blockIdx.x * 4 + (threadIdx.x >> 6);
    const int lane = threadIdx.x & 63;
    const int base = rowptr[n];
    const int deg  = rowptr[n + 1] - base;
    const float adst = a_d[n];

    float m = -1e30f;
    for (int cs = 0; cs < deg; cs += 64) {
        int e = cs + lane;
        if (e < deg) {
            float scv = a_s[csr_src[base + e]] + adst;
            scv = scv > 0.f ? scv : 0.2f * scv;
            m = fmaxf(m, scv);
        }
    }
#pragma unroll
    for (int off = 32; off > 0; off >>= 1) m = fmaxf(m, __shfl_xor(m, off));
    float den = 0.f;
    for (int cs = 0; cs < deg; cs += 64) {
        int e = cs + lane;
        if (e < deg) {
            float scv = a_s[csr_src[base + e]] + adst;
            scv = scv > 0.f ? scv : 0.2f * scv;
            den += __expf(scv - m);
        }
    }
#pragma unroll
    for (int off = 32; off > 0; off >>= 1) den += __shfl_xor(den, off);
    const float rd = 1.0f / (den + 1e-16f);

    const int c0 = lane * 12;
    float acc[12];
#pragma unroll
    for (int i = 0; i < 12; ++i) acc[i] = 0.f;

    for (int cs = 0; cs < deg; cs += 64) {
        int cnt = min(64, deg - cs);
        int e = cs + lane;
        int srcl = (e < deg) ? csr_src[base + e] : 0;
        float wv = 0.f;
        if (e < deg) {
            float scv = a_s[srcl] + adst;
            scv = scv > 0.f ? scv : 0.2f * scv;
            wv = __expf(scv - m) * rd;
        }
        for (int k = 0; k < cnt; ++k) {
            int src = __shfl(srcl, k);
            float w = __shfl(wv, k);
            const ushort_t* hp = h + (size_t)src * C_CH + c0;
            ushort4v v0 = *(const ushort4v*)(hp);
            ushort4v v1 = *(const ushort4v*)(hp + 4);
            ushort4v v2 = *(const ushort4v*)(hp + 8);
#pragma unroll
            for (int i = 0; i < 4; ++i) {
                acc[i]     += w * bf2f(v0[i]);
                acc[4 + i] += w * bf2f(v1[i]);
                acc[8 + i] += w * bf2f(v2[i]);
            }
        }
    }
#pragma unroll
    for (int p = 0; p < 3; ++p) {
        ushort_t o0 = f2bf(acc[p * 4 + 0] + bias[c0 + p * 4 + 0]);
        ushort_t o1 = f2bf(acc[p * 4 + 1] + bias[c0 + p * 4 + 1]);
        ushort_t o2 = f2bf(acc[p * 4 + 2] + bias[c0 + p * 4 + 2]);
        ushort_t o3 = f2bf(acc[p * 4 + 3] + bias[c0 + p * 4 + 3]);
        unsigned long long pk = (unsigned long long)o0 | ((unsigned long long)o1 << 16)
                              | ((unsigned long long)o2 << 32) | ((unsigned long long)o3 << 48);
        *(unsigned long long*)(out + (size_t)n * C_CH + c0 + p * 4) = pk;
    }
}

// ---------------------------------------------------------------------------
// Build fc input rows: Afc[m] = concat(out2[mask[m]], xb[mask[m]])  (bf16)
// ---------------------------------------------------------------------------
__global__ void gatherfc_kernel(const ushort_t* __restrict__ out2, const ushort_t* __restrict__ xb,
                                const int* __restrict__ maskc, ushort_t* __restrict__ Afc)
{
    int m = blockIdx.x, t = threadIdx.x;
    int mi = maskc[m];
    const ushort_t* p1 = out2 + (size_t)mi * 768;
    const ushort_t* p2 = xb   + (size_t)mi * 768;
    for (int c = t; c < 768; c += 256) {
        Afc[(size_t)m * 1536 + c]       = p1[c];
        Afc[(size_t)m * 1536 + 768 + c] = p2[c];
    }
}

// ---------------------------------------------------------------------------
// Classifier: out[m, 0:2] = fc_out[m] @ cls_w + cls_b (f32 out). One wave/row.
// ---------------------------------------------------------------------------
__global__ __launch_bounds__(256) void cls_kernel(
    const ushort_t* __restrict__ fc_out, const float* __restrict__ cls_w,
    const float* __restrict__ cls_b, float* __restrict__ out)
{
    int m = blockIdx.x * 4 + (threadIdx.x >> 6);
    int lane = threadIdx.x & 63;
    float a0 = 0.f, a1 = 0.f;
    const ushort_t* row = fc_out + (size_t)m * 768;
    for (int i = lane; i < 768; i += 64) {
        float v = bf2f(row[i]);
        a0 += v * cls_w[i * 2 + 0];
        a1 += v * cls_w[i * 2 + 1];
    }
#pragma unroll
    for (int off = 32; off > 0; off >>= 1) {
        a0 += __shfl_down(a0, off);
        a1 += __shfl_down(a1, off);
    }
    if (lane == 0) {
        out[m * 2 + 0] = a0 + cls_b[0];
        out[m * 2 + 1] = a1 + cls_b[1];
    }
}

extern "C" void kernel_launch(void* const* d_in, const int* in_sizes, int n_in,
                              void* d_out, int out_size, void* d_ws, size_t ws_size,
                              hipStream_t stream)
{
    const float* x        = (const float*)d_in[0];
    const void*  ei_raw   = d_in[1];
    const void*  mask_raw = d_in[2];
    const float* W1       = (const float*)d_in[3];
    const float* att_src1 = (const float*)d_in[4];
    const float* att_dst1 = (const float*)d_in[5];
    const float* b1       = (const float*)d_in[6];
    const float* W2       = (const float*)d_in[7];
    const float* att_src2 = (const float*)d_in[8];
    const float* att_dst2 = (const float*)d_in[9];
    const float* b2       = (const float*)d_in[10];
    const float* fc_w     = (const float*)d_in[11];
    const float* fc_b     = (const float*)d_in[12];
    const float* cls_w    = (const float*)d_in[13];
    const float* cls_b    = (const float*)d_in[14];
    float* out = (float*)d_out;

    // ---- workspace layout ----
    char* ws = (char*)d_ws;
    size_t off = 0;
    auto alloc = [&](size_t bytes) { char* p = ws + off; off = (off + bytes + 255) & ~(size_t)255; return p; };
    int*   flags  = (int*)alloc(2 * 4);
    int*   eic    = (int*)alloc((size_t)2 * E_EDGES * 4);
    int*   maskc  = (int*)alloc((size_t)M_MASK * 4);
    int*   deg    = (int*)alloc(N_NODES * 4);
    int*   fill   = (int*)alloc(N_NODES * 4);
    int*   rowptr = (int*)alloc((N_NODES + 1) * 4);
    int*   csr    = (int*)alloc(E_TOT * 4);
    float* a_s1   = (float*)alloc((size_t)N_NODES * 8 * 4);
    float* a_d1   = (float*)alloc((size_t)N_NODES * 8 * 4);
    float* a_s2   = (float*)alloc((size_t)N_NODES * 4);
    float* a_d2   = (float*)alloc((size_t)N_NODES * 4);
    float* ws1    = (float*)alloc((size_t)D_IN * 8 * 4);   // att1 algebraic weights (head-major)
    float* wd1    = (float*)alloc((size_t)D_IN * 8 * 4);
    ushort_t* W1t  = (ushort_t*)alloc((size_t)D_IN * F1 * 2);
    ushort_t* W2t  = (ushort_t*)alloc((size_t)F1 * C_CH * 2);
    ushort_t* fcwt = (ushort_t*)alloc((size_t)1536 * 768 * 2);
    ushort_t* xb   = (ushort_t*)alloc((size_t)N_NODES * D_IN * 2);
    char* region1 = alloc((size_t)N_NODES * F1 * 2);   // xagg, later h2/Afc/fcout/partials
    char* region2 = alloc((size_t)N_NODES * F1 * 2);   // out1, later out2
    ushort_t* xagg  = (ushort_t*)region1;                   // [8][8192][768] bf16 = 100.7MB
    ushort_t* h2    = (ushort_t*)region1;                   // after xagg dead (12.6MB)
    ushort_t* Afc   = (ushort_t*)(region1 + (16u << 20));   // 6.3MB @ 16MiB
    ushort_t* fcout = (ushort_t*)(region1 + (32u << 20));   // 3.1MB @ 32MiB
    ushort_t* part  = (ushort_t*)(region1 + (48u << 20));   // 4x12.6MB bf16 split-K partials @ 48MiB (xagg dead)
    ushort_t* out1  = (ushort_t*)region2;
    ushort_t* out2  = (ushort_t*)region2;                   // after out1 dead

    // ---- index conversion + CSR build ----
    init_kernel<<<N_NODES / 256, 256, 0, stream>>>(deg, fill, flags);
    detect_kernel<<<(E_EDGES + 255) / 256, 256, 0, stream>>>((const int*)ei_raw, E_EDGES, &flags[0]);
    detect_kernel<<<(M_MASK / 2 + 255) / 256, 256, 0, stream>>>((const int*)mask_raw, M_MASK / 2, &flags[1]);
    convert_idx_kernel<<<(2 * E_EDGES + 255) / 256, 256, 0, stream>>>(ei_raw, 2 * E_EDGES, &flags[0], eic);
    convert_idx_kernel<<<(M_MASK + 255) / 256, 256, 0, stream>>>(mask_raw, M_MASK, &flags[1], maskc);
    indeg_kernel<<<E_TOT / 256, 256, 0, stream>>>(eic, deg);
    scan_kernel<<<1, 256, 0, stream>>>(deg, rowptr);
    scatter_kernel<<<E_TOT / 256, 256, 0, stream>>>(eic, rowptr, fill, csr);

    // ---- converts + att1 algebraic path (all BEFORE the big GEMM) ----
    cvt_bf16_kernel<<<(N_NODES * D_IN / 4 + 255) / 256, 256, 0, stream>>>(x, xb, N_NODES * D_IN / 4);
    att1_wprep_kernel<<<(D_IN * 8) / 4, 256, 0, stream>>>(W1, att_src1, att_dst1, ws1, wd1);
    att1_gemv_kernel<<<N_NODES / 4, 256, 0, stream>>>(xb, ws1, wd1, a_s1, a_d1);
    transpose_cvt_kernel<<<dim3(F1 / 32, D_IN / 32), 256, 0, stream>>>(W1, W1t, D_IN, F1);
    transpose_cvt_kernel<<<dim3(C_CH / 32, F1 / 32), 256, 0, stream>>>(W2, W2t, F1, C_CH);
    transpose_cvt_kernel<<<dim3(768 / 32, 1536 / 32), 256, 0, stream>>>(fc_w, fcwt, 1536, 768);

    // ---- layer 1 (aggregate-then-project): no h1 materialization ----
    agg8x_kernel<<<N_NODES, 192, 0, stream>>>(xb, a_s1, a_d1, rowptr, csr, xagg);
    gemm_bd_kernel<<<NBX_BD * NBY_BD * 8, 256, 0, stream>>>(xagg, W1t, out1, b1, N_NODES, D_IN);

    // ---- layer 2 ----  (xagg dead: region1 reused for h2 + split-K partials)
    gemm_bt_splitk_kernel<<<NBX2 * NBY2 * NSPLIT, 256, 0, stream>>>(out1, W2t, part, N_NODES, C_CH, F1);
    splitk_reduce_att_kernel<<<N_NODES, 192, 0, stream>>>(
        part, h2, att_src2, att_dst2, a_s2, a_d2);
    agg1_kernel<<<N_NODES / 4, 256, 0, stream>>>(h2, a_s2, a_d2, rowptr, csr, b2, out2);  // out1 dead

    // ---- head ----
    gatherfc_kernel<<<M_MASK, 256, 0, stream>>>(out2, xb, maskc, Afc);
    gemm_bt_kernel<<<dim3(768 / 128, M_MASK / 128), 256, 0, stream>>>(Afc, fcwt, fcout, fc_b, M_MASK, 768, 1536);
    cls_kernel<<<M_MASK / 4, 256, 0, stream>>>(fcout, cls_w, cls_b, out);
}

// Round 16
// 463.418 us; speedup vs baseline: 1.7828x; 1.0094x over previous
//
#include <hip/hip_runtime.h>

typedef unsigned short ushort_t;
typedef __attribute__((ext_vector_type(8))) __bf16 bf16x8;
typedef __attribute__((ext_vector_type(8))) unsigned short ushort8;
typedef __attribute__((ext_vector_type(4))) unsigned short ushort4v;
typedef __attribute__((ext_vector_type(4))) float f32x4;

#define N_NODES 8192
#define NODE_MASK 8191
#define E_EDGES 32768
#define E_TOT   40960   /* E + N self loops */
#define M_MASK  2048
#define D_IN    768
#define C_CH    768
#define F1      6144    /* 8 heads * 768 */

typedef __attribute__((address_space(1))) const void* gas_ptr;
typedef __attribute__((address_space(3))) void* las_ptr;

__device__ __forceinline__ float bf2f(ushort_t u) {
    union { unsigned int i; float f; } v; v.i = ((unsigned int)u) << 16; return v.f;
}
__device__ __forceinline__ ushort_t f2bf(float f) {
    union { float f; unsigned int i; } v; v.f = f;
    unsigned int r = v.i + 0x7fffu + ((v.i >> 16) & 1u);
    return (ushort_t)(r >> 16);
}

// ---------------------------------------------------------------------------
// int64-vs-int32 detection + conversion of index arrays (clamped to [0,N)).
// detect stays SEPARATE per array with per-wave __any -> 1 atomicOr/wave
// (R14: merged detect with divergent atomic address = 385 us serialization).
// convert IS merged (no atomics -> safe).
// ---------------------------------------------------------------------------
__global__ void init_kernel(int* deg, int* fill, int* flags) {
    int i = blockIdx.x * 256 + threadIdx.x;
    if (i < N_NODES) { deg[i] = 0; fill[i] = 0; }
    if (i < 2) flags[i] = 0;
}
__global__ void detect_kernel(const int* __restrict__ raw, int nhalf, int* __restrict__ flag) {
    int i = blockIdx.x * 256 + threadIdx.x;
    bool nz = (i < nhalf) && (raw[2 * i + 1] != 0);
    if (__any(nz) && (threadIdx.x & 63) == 0) atomicOr(flag, 1);
}
__global__ void convert2_kernel(const void* __restrict__ ei_raw, const void* __restrict__ mask_raw,
                                const int* __restrict__ flags,
                                int* __restrict__ eic, int* __restrict__ maskc) {
    int i = blockIdx.x * 256 + threadIdx.x;
    if (i < 2 * E_EDGES) {
        int v = flags[0] ? ((const int*)ei_raw)[i] : (int)((const long long*)ei_raw)[i];
        eic[i] = v & NODE_MASK;
    } else {
        int j = i - 2 * E_EDGES;
        if (j < M_MASK) {
            int v = flags[1] ? ((const int*)mask_raw)[j] : (int)((const long long*)mask_raw)[j];
            maskc[j] = v & NODE_MASK;
        }
    }
}

// ---------------------------------------------------------------------------
// f32 -> bf16 elementwise convert (vectorized)
// ---------------------------------------------------------------------------
__global__ void cvt_bf16_kernel(const float* __restrict__ in, ushort_t* __restrict__ out, int n4) {
    int i = blockIdx.x * 256 + threadIdx.x;
    if (i >= n4) return;
    f32x4 v = *(const f32x4*)(in + i * 4);
    ushort_t o0 = f2bf(v[0]), o1 = f2bf(v[1]), o2 = f2bf(v[2]), o3 = f2bf(v[3]);
    unsigned long long pk = (unsigned long long)o0 | ((unsigned long long)o1 << 16)
                          | ((unsigned long long)o2 << 32) | ((unsigned long long)o3 << 48);
    *(unsigned long long*)(out + i * 4) = pk;
}

// ---------------------------------------------------------------------------
// f32 -> bf16 transpose: out[c][r] = (bf16)in[r][c]; in is R x Ccols f32.
// ---------------------------------------------------------------------------
__global__ __launch_bounds__(256) void transpose_cvt_kernel(
    const float* __restrict__ in, ushort_t* __restrict__ out, int R, int Ccols)
{
    __shared__ ushort_t tile[32][33];
    int tx = threadIdx.x & 31, ty = threadIdx.x >> 5;
    int x  = blockIdx.x * 32 + tx;
    int y0 = blockIdx.y * 32;
#pragma unroll
    for (int i = 0; i < 4; ++i)
        tile[ty + i * 8][tx] = f2bf(in[(size_t)(y0 + ty + i * 8) * Ccols + x]);
    __syncthreads();
#pragma unroll
    for (int i = 0; i < 4; ++i)
        out[(size_t)(blockIdx.x * 32 + ty + i * 8) * R + y0 + tx] = tile[tx][ty + i * 8];
}

// ---------------------------------------------------------------------------
// bf16 MFMA GEMM:  C[M,N] = A[M,K] * Bt[N,K]^T  (+ optional f32 bias[N]) -> bf16
// 128x128 tile, BK=64, 256 threads (m97 structure, 84 VGPR). Used for head GEMM.
// ---------------------------------------------------------------------------
__global__ __launch_bounds__(256) void gemm_bt_kernel(
    const ushort_t* __restrict__ A, const ushort_t* __restrict__ Bt,
    ushort_t* __restrict__ C, const float* __restrict__ bias,
    int M, int N, int K)
{
    __shared__ ushort_t lsA[128 * 64];
    __shared__ ushort_t lsB[128 * 64];

    const int tid  = threadIdx.x;
    const int lane = tid & 63;
    const int wave = tid >> 6;
    const int wm = wave >> 1, wn = wave & 1;
    const int bx = blockIdx.x, by = blockIdx.y;

    const f32x4 zero = {0.f, 0.f, 0.f, 0.f};
    f32x4 acc[4][4];
#pragma unroll
    for (int i = 0; i < 4; ++i)
#pragma unroll
        for (int j = 0; j < 4; ++j) acc[i][j] = zero;

    const int l8 = lane >> 3;   // row within 8-row group
    const int c8 = lane & 7;    // 16B chunk slot
    const int q  = lane >> 4;   // quad
    const int rl = lane & 15;

    for (int kt = 0; kt < K; kt += 64) {
        __syncthreads();   // previous tile fully consumed
#pragma unroll
        for (int i = 0; i < 4; ++i) {
            int rbase = wave * 32 + i * 8;      // wave-uniform
            int row   = rbase + l8;             // per-lane
            int gch   = c8 ^ (row & 7);         // swizzle on source
            const ushort_t* gA = A  + (size_t)(by * 128 + row) * K + kt + gch * 8;
            const ushort_t* gB = Bt + (size_t)(bx * 128 + row) * K + kt + gch * 8;
            __builtin_amdgcn_global_load_lds((gas_ptr)gA, (las_ptr)(lsA + rbase * 64), 16, 0, 0);
            __builtin_amdgcn_global_load_lds((gas_ptr)gB, (las_ptr)(lsB + rbase * 64), 16, 0, 0);
        }
        __syncthreads();   // vmcnt drained by barrier semantics
#pragma unroll
        for (int s = 0; s < 2; ++s) {
            bf16x8 af[4], bfv[4];
#pragma unroll
            for (int i = 0; i < 4; ++i) {
                int Ra = wm * 64 + i * 16 + rl;
                af[i]  = *(const bf16x8*)(lsA + Ra * 64 + (((s * 4 + q) ^ (Ra & 7)) * 8));
                int Rb = wn * 64 + i * 16 + rl;
                bfv[i] = *(const bf16x8*)(lsB + Rb * 64 + (((s * 4 + q) ^ (Rb & 7)) * 8));
            }
#pragma unroll
            for (int i = 0; i < 4; ++i)
#pragma unroll
                for (int j = 0; j < 4; ++j)
                    acc[i][j] = __builtin_amdgcn_mfma_f32_16x16x32_bf16(af[i], bfv[j], acc[i][j], 0, 0, 0);
        }
    }
    // epilogue: C/D layout col=lane&15, row=quad*4+reg (m89-verified)
#pragma unroll
    for (int j = 0; j < 4; ++j) {
        int col = bx * 128 + wn * 64 + j * 16 + rl;
        float bv = bias ? bias[col] : 0.0f;
#pragma unroll
        for (int i = 0; i < 4; ++i) {
#pragma unroll
            for (int t = 0; t < 4; ++t) {
                int row = by * 128 + wm * 64 + i * 16 + q * 4 + t;
                C[(size_t)row * N + col] = f2bf(acc[i][j][t] + bv);
            }
        }
    }
}

// ---------------------------------------------------------------------------
// Per-head block-diagonal GEMM for layer 1 (aggregate-then-project algebra):
//   out1[n, h*768+c] = ELU( b1[h*768+c] + xagg_h[n,:] @ W1t[h*768+c,:] )
// Linear grid of 3072 blocks with XCD-aware panel-grouping decode; head==xcd
// so each XCD's W1t panel + xagg slice stay L2-resident (FETCH 314->66MB).
// bias+ELU fused in-place on acc.
// ---------------------------------------------------------------------------
#define NBX_BD 6     /* 768/128 */
#define NBY_BD 64    /* 8192/128 */

__global__ __launch_bounds__(256) void gemm_bd_kernel(
    const ushort_t* __restrict__ A0, const ushort_t* __restrict__ Bt0,
    ushort_t* __restrict__ C, const float* __restrict__ bias,
    int M, int K)
{
    __shared__ ushort_t lsA[128 * 64];
    __shared__ ushort_t lsB[128 * 64];

    const int tid  = threadIdx.x;
    const int lane = tid & 63;
    const int wave = tid >> 6;
    const int wm = wave >> 1, wn = wave & 1;

    // XCD-aware bijective decode (3072 blocks, 8 XCDs, 64 panel-groups/XCD)
    const int d    = blockIdx.x;
    const int xcd  = d & 7;
    const int slot = d >> 3;                 // 0..383
    const int bx   = slot % NBX_BD;          // 0..5
    const int grp  = xcd * 64 + slot / NBX_BD;   // 0..511
    const int by   = grp & (NBY_BD - 1);
    const int head = grp >> 6;               // == xcd

    const ushort_t* A  = A0  + (size_t)head * M * K;
    const ushort_t* Bt = Bt0 + (size_t)head * C_CH * K;

    const f32x4 zero = {0.f, 0.f, 0.f, 0.f};
    f32x4 acc[4][4];
#pragma unroll
    for (int i = 0; i < 4; ++i)
#pragma unroll
        for (int j = 0; j < 4; ++j) acc[i][j] = zero;

    const int l8 = lane >> 3;
    const int c8 = lane & 7;
    const int q  = lane >> 4;
    const int rl = lane & 15;

    for (int kt = 0; kt < K; kt += 64) {
        __syncthreads();
#pragma unroll
        for (int i = 0; i < 4; ++i) {
            int rbase = wave * 32 + i * 8;
            int row   = rbase + l8;
            int gch   = c8 ^ (row & 7);
            const ushort_t* gA = A  + (size_t)(by * 128 + row) * K + kt + gch * 8;
            const ushort_t* gB = Bt + (size_t)(bx * 128 + row) * K + kt + gch * 8;
            __builtin_amdgcn_global_load_lds((gas_ptr)gA, (las_ptr)(lsA + rbase * 64), 16, 0, 0);
            __builtin_amdgcn_global_load_lds((gas_ptr)gB, (las_ptr)(lsB + rbase * 64), 16, 0, 0);
        }
        __syncthreads();
#pragma unroll
        for (int s = 0; s < 2; ++s) {
            bf16x8 af[4], bfv[4];
#pragma unroll
            for (int i = 0; i < 4; ++i) {
                int Ra = wm * 64 + i * 16 + rl;
                af[i]  = *(const bf16x8*)(lsA + Ra * 64 + (((s * 4 + q) ^ (Ra & 7)) * 8));
                int Rb = wn * 64 + i * 16 + rl;
                bfv[i] = *(const bf16x8*)(lsB + Rb * 64 + (((s * 4 + q) ^ (Rb & 7)) * 8));
            }
#pragma unroll
            for (int i = 0; i < 4; ++i)
#pragma unroll
                for (int j = 0; j < 4; ++j)
                    acc[i][j] = __builtin_amdgcn_mfma_f32_16x16x32_bf16(af[i], bfv[j], acc[i][j], 0, 0, 0);
        }
    }
    // epilogue: bias + ELU fused, store into the full 6144-wide out1
#pragma unroll
    for (int j = 0; j < 4; ++j) {
        int colf = head * C_CH + bx * 128 + wn * 64 + j * 16 + rl;
        float bv = bias[colf];
#pragma unroll
        for (int i = 0; i < 4; ++i) {
#pragma unroll
            for (int t = 0; t < 4; ++t) {
                int row = by * 128 + wm * 64 + i * 16 + q * 4 + t;
                float v = acc[i][j][t] + bv;
                v = v > 0.f ? v : (__expf(v) - 1.0f);   // ELU
                C[(size_t)row * F1 + colf] = f2bf(v);
            }
        }
    }
}

// ---------------------------------------------------------------------------
// Split-K variant for the N=768 layer-2 GEMM, NSPLIT=4, bf16 partials.
// 1536 blocks = 6/CU dispatched for latency hiding; bf16 partials keep
// total partial traffic equal to the old f32 x2 scheme. XCD decode: all 6
// bx-blocks of one A-panel on one XCD.
// ---------------------------------------------------------------------------
#define NBX2 6      /* N=768 / 128 */
#define NBY2 64     /* M=8192 / 128 */
#define NSPLIT 4

__global__ __launch_bounds__(256) void gemm_bt_splitk_kernel(
    const ushort_t* __restrict__ A, const ushort_t* __restrict__ Bt,
    ushort_t* __restrict__ Cpart, int M, int N, int K)
{
    __shared__ ushort_t lsA[128 * 64];
    __shared__ ushort_t lsB[128 * 64];

    const int tid  = threadIdx.x;
    const int lane = tid & 63;
    const int wave = tid >> 6;
    const int wm = wave >> 1, wn = wave & 1;

    // XCD-aware bijective decode (1536 blocks, 8 XCDs, 32 panel-groups/XCD)
    const int d    = blockIdx.x;
    const int xcd  = d & 7;
    const int slot = d >> 3;                  // 0..191
    const int bx   = slot % NBX2;             // 0..5
    const int grp  = xcd * 32 + slot / NBX2;  // 0..255
    const int by   = grp & (NBY2 - 1);        // 0..63
    const int bz   = grp >> 6;                // 0..3

    const int kh  = K >> 2;
    const int kt0 = bz * kh;
    ushort_t* __restrict__ Cp = Cpart + (size_t)bz * M * N;

    const f32x4 zero = {0.f, 0.f, 0.f, 0.f};
    f32x4 acc[4][4];
#pragma unroll
    for (int i = 0; i < 4; ++i)
#pragma unroll
        for (int j = 0; j < 4; ++j) acc[i][j] = zero;

    const int l8 = lane >> 3;
    const int c8 = lane & 7;
    const int q  = lane >> 4;
    const int rl = lane & 15;

    for (int kt = kt0; kt < kt0 + kh; kt += 64) {
        __syncthreads();
#pragma unroll
        for (int i = 0; i < 4; ++i) {
            int rbase = wave * 32 + i * 8;
            int row   = rbase + l8;
            int gch   = c8 ^ (row & 7);
            const ushort_t* gA = A  + (size_t)(by * 128 + row) * K + kt + gch * 8;
            const ushort_t* gB = Bt + (size_t)(bx * 128 + row) * K + kt + gch * 8;
            __builtin_amdgcn_global_load_lds((gas_ptr)gA, (las_ptr)(lsA + rbase * 64), 16, 0, 0);
            __builtin_amdgcn_global_load_lds((gas_ptr)gB, (las_ptr)(lsB + rbase * 64), 16, 0, 0);
        }
        __syncthreads();
#pragma unroll
        for (int s = 0; s < 2; ++s) {
            bf16x8 af[4], bfv[4];
#pragma unroll
            for (int i = 0; i < 4; ++i) {
                int Ra = wm * 64 + i * 16 + rl;
                af[i]  = *(const bf16x8*)(lsA + Ra * 64 + (((s * 4 + q) ^ (Ra & 7)) * 8));
                int Rb = wn * 64 + i * 16 + rl;
                bfv[i] = *(const bf16x8*)(lsB + Rb * 64 + (((s * 4 + q) ^ (Rb & 7)) * 8));
            }
#pragma unroll
            for (int i = 0; i < 4; ++i)
#pragma unroll
                for (int j = 0; j < 4; ++j)
                    acc[i][j] = __builtin_amdgcn_mfma_f32_16x16x32_bf16(af[i], bfv[j], acc[i][j], 0, 0, 0);
        }
    }
#pragma unroll
    for (int j = 0; j < 4; ++j) {
        int col = bx * 128 + wn * 64 + j * 16 + rl;
#pragma unroll
        for (int i = 0; i < 4; ++i) {
#pragma unroll
            for (int t = 0; t < 4; ++t) {
                int row = by * 128 + wm * 64 + i * 16 + q * 4 + t;
                Cp[(size_t)row * N + col] = f2bf(acc[i][j][t]);
            }
        }
    }
}

// ---------------------------------------------------------------------------
// Split-K reduce (4 bf16 partials) + fused layer-2 attention logits.
// One 192-thread block per node: h2[n] = sum_k Pk[n] -> bf16, and
// a_s2/a_d2 via block reduce. No atomics.
// ---------------------------------------------------------------------------
__global__ __launch_bounds__(192) void splitk_reduce_att_kernel(
    const ushort_t* __restrict__ P, ushort_t* __restrict__ out,
    const float* __restrict__ as2, const float* __restrict__ ad2,
    float* __restrict__ a_s, float* __restrict__ a_d)
{
    const int n = blockIdx.x, tid = threadIdx.x;
    const int c0 = tid * 4;
    float v[4] = {0.f, 0.f, 0.f, 0.f};
#pragma unroll
    for (int k = 0; k < NSPLIT; ++k) {
        ushort4v p = *(const ushort4v*)(P + ((size_t)k * N_NODES + n) * C_CH + c0);
#pragma unroll
        for (int t = 0; t < 4; ++t) v[t] += bf2f(p[t]);
    }
    f32x4 ws = *(const f32x4*)(as2 + c0);
    f32x4 wd = *(const f32x4*)(ad2 + c0);
    float s1 = 0.f, s2 = 0.f;
    ushort_t o[4];
#pragma unroll
    for (int t = 0; t < 4; ++t) {
        o[t] = f2bf(v[t]);
        s1 += v[t] * ws[t];
        s2 += v[t] * wd[t];
    }
    unsigned long long pk = (unsigned long long)o[0] | ((unsigned long long)o[1] << 16)
                          | ((unsigned long long)o[2] << 32) | ((unsigned long long)o[3] << 48);
    *(unsigned long long*)(out + (size_t)n * C_CH + c0) = pk;

    __shared__ float red[2][3];
#pragma unroll
    for (int off = 32; off > 0; off >>= 1) {
        s1 += __shfl_down(s1, off);
        s2 += __shfl_down(s2, off);
    }
    const int lane = tid & 63, wv = tid >> 6;
    if (lane == 0) { red[0][wv] = s1; red[1][wv] = s2; }
    __syncthreads();
    if (tid == 0) {
        a_s[n] = red[0][0] + red[0][1] + red[0][2];
        a_d[n] = red[1][0] + red[1][1] + red[1][2];
    }
}

// ---------------------------------------------------------------------------
// CSR build by dst (count -> scan -> scatter). Indices pre-clamped to [0,N).
// ---------------------------------------------------------------------------
__global__ void indeg_kernel(const int* __restrict__ eic, int* __restrict__ deg) {
    int e = blockIdx.x * 256 + threadIdx.x;
    if (e >= E_TOT) return;
    int dst = (e < E_EDGES) ? eic[E_EDGES + e] : (e - E_EDGES);
    atomicAdd(&deg[dst], 1);
}
__global__ __launch_bounds__(256) void scan_kernel(const int* __restrict__ deg, int* __restrict__ rowptr) {
    __shared__ int part[256];
    int t = threadIdx.x;
    int local[32];
    int s = 0;
#pragma unroll
    for (int i = 0; i < 32; ++i) { local[i] = deg[t * 32 + i]; s += local[i]; }
    part[t] = s;
    __syncthreads();
    for (int off = 1; off < 256; off <<= 1) {
        int v = (t >= off) ? part[t - off] : 0;
        __syncthreads();
        part[t] += v;
        __syncthreads();
    }
    int run = (t == 0) ? 0 : part[t - 1];
#pragma unroll
    for (int i = 0; i < 32; ++i) { rowptr[t * 32 + i] = run; run += local[i]; }
    if (t == 255) rowptr[N_NODES] = run;
}
__global__ void scatter_kernel(const int* __restrict__ eic, const int* __restrict__ rowptr,
                               int* __restrict__ fill, int* __restrict__ csr_src) {
    int e = blockIdx.x * 256 + threadIdx.x;
    if (e >= E_TOT) return;
    int src, dst;
    if (e < E_EDGES) { src = eic[e]; dst = eic[E_EDGES + e]; }
    else             { src = e - E_EDGES; dst = src; }
    int pos = rowptr[dst] + atomicAdd(&fill[dst], 1);
    csr_src[pos] = src;
}

// ---------------------------------------------------------------------------
// Layer-1 attention weight precompute (algebraic fusion), HEAD-MAJOR layout:
//   ws[h*768+d] = sum_c W1[d][h*768+c] * att_src1[h][c]. One wave per (d,h),
//   1536 blocks.
// ---------------------------------------------------------------------------
__global__ __launch_bounds__(256) void att1_wprep_kernel(
    const float* __restrict__ W1, const float* __restrict__ att_s,
    const float* __restrict__ att_d, float* __restrict__ ws, float* __restrict__ wd)
{
    int gid  = blockIdx.x * 4 + (threadIdx.x >> 6);   // 0..6143
    int lane = threadIdx.x & 63;
    int d = gid >> 3, h = gid & 7;
    const float* wp = W1 + (size_t)d * F1 + h * C_CH;
    const float* sp = att_s + h * C_CH;
    const float* dp = att_d + h * C_CH;
    float s1 = 0.f, s2 = 0.f;
#pragma unroll
    for (int j = 0; j < 3; ++j) {
        int o = j * 256 + lane * 4;
        f32x4 w  = *(const f32x4*)(wp + o);
        f32x4 sv = *(const f32x4*)(sp + o);
        f32x4 dv = *(const f32x4*)(dp + o);
#pragma unroll
        for (int k = 0; k < 4; ++k) { s1 += w[k] * sv[k]; s2 += w[k] * dv[k]; }
    }
#pragma unroll
    for (int off = 32; off > 0; off >>= 1) {
        s1 += __shfl_down(s1, off);
        s2 += __shfl_down(s2, off);
    }
    if (lane == 0) { ws[h * D_IN + d] = s1; wd[h * D_IN + d] = s2; }
}

// ---------------------------------------------------------------------------
// Layer-1 attention logits as a tiny GEMV: a_s1[n,h] = <xb[n,:], ws[h,:]>.
// One wave per node; fully coalesced f32x4 weight reads (head-major).
// ---------------------------------------------------------------------------
__global__ __launch_bounds__(256) void att1_gemv_kernel(
    const ushort_t* __restrict__ xb, const float* __restrict__ ws,
    const float* __restrict__ wd, float* __restrict__ a_s, float* __restrict__ a_d)
{
    int n    = blockIdx.x * 4 + (threadIdx.x >> 6);
    int lane = threadIdx.x & 63;
    const ushort_t* xp = xb + (size_t)n * D_IN;
    float s[8], d[8];
#pragma unroll
    for (int h = 0; h < 8; ++h) { s[h] = 0.f; d[h] = 0.f; }
#pragma unroll
    for (int j = 0; j < 3; ++j) {
        int d0 = j * 256 + lane * 4;
        ushort4v xv = *(const ushort4v*)(xp + d0);
        float xf0 = bf2f(xv[0]), xf1 = bf2f(xv[1]), xf2 = bf2f(xv[2]), xf3 = bf2f(xv[3]);
#pragma unroll
        for (int h = 0; h < 8; ++h) {
            f32x4 wv = *(const f32x4*)(ws + (size_t)h * D_IN + d0);
            f32x4 dv = *(const f32x4*)(wd + (size_t)h * D_IN + d0);
            s[h] += xf0 * wv[0] + xf1 * wv[1] + xf2 * wv[2] + xf3 * wv[3];
            d[h] += xf0 * dv[0] + xf1 * dv[1] + xf2 * dv[2] + xf3 * dv[3];
        }
    }
#pragma unroll
    for (int h = 0; h < 8; ++h) {
#pragma unroll
        for (int off = 32; off > 0; off >>= 1) {
            s[h] += __shfl_down(s[h], off);
            d[h] += __shfl_down(d[h], off);
        }
    }
    if (lane == 0) {
#pragma unroll
        for (int h = 0; h < 8; ++h) { a_s[n * 8 + h] = s[h]; a_d[n * 8 + h] = d[h]; }
    }
}

// ---------------------------------------------------------------------------
// Layer-1 aggregation IN X-SPACE (aggregate-then-project):
//   xagg[h][n][d] = sum_e alpha_e^h * xb[src_e][d]   (f32 accum -> bf16)
// One 192-thread block per node; thread owns 4 channels x 8 heads (32 f32).
// Each edge's x-row is read ONCE and reused for all 8 heads.
// ---------------------------------------------------------------------------
__global__ __launch_bounds__(192) void agg8x_kernel(
    const ushort_t* __restrict__ xb, const float* __restrict__ a_s, const float* __restrict__ a_d,
    const int* __restrict__ rowptr, const int* __restrict__ csr_src,
    ushort_t* __restrict__ xagg)
{
    const int n = blockIdx.x;
    const int tid = threadIdx.x;
    const int base = rowptr[n];
    const int deg  = rowptr[n + 1] - base;

    __shared__ float s_m[8], s_rd[8], s_adst[8];
    __shared__ int   s_src[64];
    __shared__ float s_w[64][8];

    if (tid < 8) {
        float adst = a_d[n * 8 + tid];
        float m = -1e30f;
        for (int e = 0; e < deg; ++e) {
            float scv = a_s[csr_src[base + e] * 8 + tid] + adst;
            scv = scv > 0.f ? scv : 0.2f * scv;
            m = fmaxf(m, scv);
        }
        float den = 0.f;
        for (int e = 0; e < deg; ++e) {
            float scv = a_s[csr_src[base + e] * 8 + tid] + adst;
            scv = scv > 0.f ? scv : 0.2f * scv;
            den += __expf(scv - m);
        }
        s_m[tid] = m; s_rd[tid] = 1.0f / (den + 1e-16f); s_adst[tid] = adst;
    }
    __syncthreads();

    float acc[8][4];
#pragma unroll
    for (int h = 0; h < 8; ++h)
#pragma unroll
        for (int i = 0; i < 4; ++i) acc[h][i] = 0.f;
    const int c0 = tid * 4;   // 192*4 = 768 channels

    for (int cs = 0; cs < deg; cs += 64) {
        int cnt = min(64, deg - cs);
        __syncthreads();
        for (int idx = tid; idx < cnt; idx += 192) s_src[idx] = csr_src[base + cs + idx];
        __syncthreads();
        for (int idx = tid; idx < cnt * 8; idx += 192) {
            int e = idx >> 3, hd = idx & 7;
            float scv = a_s[s_src[e] * 8 + hd] + s_adst[hd];
            scv = scv > 0.f ? scv : 0.2f * scv;
            s_w[e][hd] = __expf(scv - s_m[hd]) * s_rd[hd];
        }
        __syncthreads();
        for (int e = 0; e < cnt; ++e) {
            const ushort_t* xp = xb + (size_t)s_src[e] * D_IN + c0;
            ushort4v xv = *(const ushort4v*)(xp);
            float xf0 = bf2f(xv[0]), xf1 = bf2f(xv[1]), xf2 = bf2f(xv[2]), xf3 = bf2f(xv[3]);
#pragma unroll
            for (int h = 0; h < 8; ++h) {
                float w = s_w[e][h];
                acc[h][0] += w * xf0;
                acc[h][1] += w * xf1;
                acc[h][2] += w * xf2;
                acc[h][3] += w * xf3;
            }
        }
    }
#pragma unroll
    for (int h = 0; h < 8; ++h) {
        ushort_t o0 = f2bf(acc[h][0]), o1 = f2bf(acc[h][1]);
        ushort_t o2 = f2bf(acc[h][2]), o3 = f2bf(acc[h][3]);
        unsigned long long pk = (unsigned long long)o0 | ((unsigned long long)o1 << 16)
                              | ((unsigned long long)o2 << 32) | ((unsigned long long)o3 << 48);
        *(unsigned long long*)(xagg + ((size_t)h * N_NODES + n) * D_IN + c0) = pk;
    }
}

// ---------------------------------------------------------------------------
// Aggregation layer 2 (1 head, 768 ch): ONE WAVE per node (4 nodes/block).
// Lane owns 12 channels (3 x ushort4 8B loads); wave-parallel softmax stats;
// per-edge weight broadcast via shfl. Zero barriers.
// ---------------------------------------------------------------------------
__global__ __launch_bounds__(256) void agg1_kernel(
    const ushort_t* __restrict__ h, const float* __restrict__ a_s, const float* __restrict__ a_d,
    const int* __restrict__ rowptr, const int* __restrict__ csr_src,
    const float* __restrict__ bias, ushort_t* __restrict__ out)
{
    const int n    = blockIdx.x * 4 + (threadIdx.x >> 6);
    const int lane = threadIdx.x & 63;
    const int base = rowptr[n];
    const int deg  = rowptr[n + 1] - base;
    const float adst = a_d[n];

    float m = -1e30f;
    for (int cs = 0; cs < deg; cs += 64) {
        int e = cs + lane;
        if (e < deg) {
            float scv = a_s[csr_src[base + e]] + adst;
            scv = scv > 0.f ? scv : 0.2f * scv;
            m = fmaxf(m, scv);
        }
    }
#pragma unroll
    for (int off = 32; off > 0; off >>= 1) m = fmaxf(m, __shfl_xor(m, off));
    float den = 0.f;
    for (int cs = 0; cs < deg; cs += 64) {
        int e = cs + lane;
        if (e < deg) {
            float scv = a_s[csr_src[base + e]] + adst;
            scv = scv > 0.f ? scv : 0.2f * scv;
            den += __expf(scv - m);
        }
    }
#pragma unroll
    for (int off = 32; off > 0; off >>= 1) den += __shfl_xor(den, off);
    const float rd = 1.0f / (den + 1e-16f);

    const int c0 = lane * 12;
    float acc[12];
#pragma unroll
    for (int i = 0; i < 12; ++i) acc[i] = 0.f;

    for (int cs = 0; cs < deg; cs += 64) {
        int cnt = min(64, deg - cs);
        int e = cs + lane;
        int srcl = (e < deg) ? csr_src[base + e] : 0;
        float wv = 0.f;
        if (e < deg) {
            float scv = a_s[srcl] + adst;
            scv = scv > 0.f ? scv : 0.2f * scv;
            wv = __expf(scv - m) * rd;
        }
        for (int k = 0; k < cnt; ++k) {
            int src = __shfl(srcl, k);
            float w = __shfl(wv, k);
            const ushort_t* hp = h + (size_t)src * C_CH + c0;
            ushort4v v0 = *(const ushort4v*)(hp);
            ushort4v v1 = *(const ushort4v*)(hp + 4);
            ushort4v v2 = *(const ushort4v*)(hp + 8);
#pragma unroll
            for (int i = 0; i < 4; ++i) {
                acc[i]     += w * bf2f(v0[i]);
                acc[4 + i] += w * bf2f(v1[i]);
                acc[8 + i] += w * bf2f(v2[i]);
            }
        }
    }
#pragma unroll
    for (int p = 0; p < 3; ++p) {
        ushort_t o0 = f2bf(acc[p * 4 + 0] + bias[c0 + p * 4 + 0]);
        ushort_t o1 = f2bf(acc[p * 4 + 1] + bias[c0 + p * 4 + 1]);
        ushort_t o2 = f2bf(acc[p * 4 + 2] + bias[c0 + p * 4 + 2]);
        ushort_t o3 = f2bf(acc[p * 4 + 3] + bias[c0 + p * 4 + 3]);
        unsigned long long pk = (unsigned long long)o0 | ((unsigned long long)o1 << 16)
                              | ((unsigned long long)o2 << 32) | ((unsigned long long)o3 << 48);
        *(unsigned long long*)(out + (size_t)n * C_CH + c0 + p * 4) = pk;
    }
}

// ---------------------------------------------------------------------------
// Build fc input rows: Afc[m] = concat(out2[mask[m]], xb[mask[m]])  (bf16)
// ---------------------------------------------------------------------------
__global__ void gatherfc_kernel(const ushort_t* __restrict__ out2, const ushort_t* __restrict__ xb,
                                const int* __restrict__ maskc, ushort_t* __restrict__ Afc)
{
    int m = blockIdx.x, t = threadIdx.x;
    int mi = maskc[m];
    const ushort_t* p1 = out2 + (size_t)mi * 768;
    const ushort_t* p2 = xb   + (size_t)mi * 768;
    for (int c = t; c < 768; c += 256) {
        Afc[(size_t)m * 1536 + c]       = p1[c];
        Afc[(size_t)m * 1536 + 768 + c] = p2[c];
    }
}

// ---------------------------------------------------------------------------
// Classifier: out[m, 0:2] = fc_out[m] @ cls_w + cls_b (f32 out). One wave/row.
// ---------------------------------------------------------------------------
__global__ __launch_bounds__(256) void cls_kernel(
    const ushort_t* __restrict__ fc_out, const float* __restrict__ cls_w,
    const float* __restrict__ cls_b, float* __restrict__ out)
{
    int m = blockIdx.x * 4 + (threadIdx.x >> 6);
    int lane = threadIdx.x & 63;
    float a0 = 0.f, a1 = 0.f;
    const ushort_t* row = fc_out + (size_t)m * 768;
    for (int i = lane; i < 768; i += 64) {
        float v = bf2f(row[i]);
        a0 += v * cls_w[i * 2 + 0];
        a1 += v * cls_w[i * 2 + 1];
    }
#pragma unroll
    for (int off = 32; off > 0; off >>= 1) {
        a0 += __shfl_down(a0, off);
        a1 += __shfl_down(a1, off);
    }
    if (lane == 0) {
        out[m * 2 + 0] = a0 + cls_b[0];
        out[m * 2 + 1] = a1 + cls_b[1];
    }
}

extern "C" void kernel_launch(void* const* d_in, const int* in_sizes, int n_in,
                              void* d_out, int out_size, void* d_ws, size_t ws_size,
                              hipStream_t stream)
{
    const float* x        = (const float*)d_in[0];
    const void*  ei_raw   = d_in[1];
    const void*  mask_raw = d_in[2];
    const float* W1       = (const float*)d_in[3];
    const float* att_src1 = (const float*)d_in[4];
    const float* att_dst1 = (const float*)d_in[5];
    const float* b1       = (const float*)d_in[6];
    const float* W2       = (const float*)d_in[7];
    const float* att_src2 = (const float*)d_in[8];
    const float* att_dst2 = (const float*)d_in[9];
    const float* b2       = (const float*)d_in[10];
    const float* fc_w     = (const float*)d_in[11];
    const float* fc_b     = (const float*)d_in[12];
    const float* cls_w    = (const float*)d_in[13];
    const float* cls_b    = (const float*)d_in[14];
    float* out = (float*)d_out;

    // ---- workspace layout ----
    char* ws = (char*)d_ws;
    size_t off = 0;
    auto alloc = [&](size_t bytes) { char* p = ws + off; off = (off + bytes + 255) & ~(size_t)255; return p; };
    int*   flags  = (int*)alloc(2 * 4);
    int*   eic    = (int*)alloc((size_t)2 * E_EDGES * 4);
    int*   maskc  = (int*)alloc((size_t)M_MASK * 4);
    int*   deg    = (int*)alloc(N_NODES * 4);
    int*   fill   = (int*)alloc(N_NODES * 4);
    int*   rowptr = (int*)alloc((N_NODES + 1) * 4);
    int*   csr    = (int*)alloc(E_TOT * 4);
    float* a_s1   = (float*)alloc((size_t)N_NODES * 8 * 4);
    float* a_d1   = (float*)alloc((size_t)N_NODES * 8 * 4);
    float* a_s2   = (float*)alloc((size_t)N_NODES * 4);
    float* a_d2   = (float*)alloc((size_t)N_NODES * 4);
    float* ws1    = (float*)alloc((size_t)D_IN * 8 * 4);   // att1 algebraic weights (head-major)
    float* wd1    = (float*)alloc((size_t)D_IN * 8 * 4);
    ushort_t* W1t  = (ushort_t*)alloc((size_t)D_IN * F1 * 2);
    ushort_t* W2t  = (ushort_t*)alloc((size_t)F1 * C_CH * 2);
    ushort_t* fcwt = (ushort_t*)alloc((size_t)1536 * 768 * 2);
    ushort_t* xb   = (ushort_t*)alloc((size_t)N_NODES * D_IN * 2);
    char* region1 = alloc((size_t)N_NODES * F1 * 2);   // xagg, later h2/Afc/fcout/partials
    char* region2 = alloc((size_t)N_NODES * F1 * 2);   // out1, later out2
    ushort_t* xagg  = (ushort_t*)region1;                   // [8][8192][768] bf16 = 100.7MB
    ushort_t* h2    = (ushort_t*)region1;                   // after xagg dead (12.6MB)
    ushort_t* Afc   = (ushort_t*)(region1 + (16u << 20));   // 6.3MB @ 16MiB
    ushort_t* fcout = (ushort_t*)(region1 + (32u << 20));   // 3.1MB @ 32MiB
    ushort_t* part  = (ushort_t*)(region1 + (48u << 20));   // 4x12.6MB bf16 split-K partials @ 48MiB (xagg dead)
    ushort_t* out1  = (ushort_t*)region2;
    ushort_t* out2  = (ushort_t*)region2;                   // after out1 dead

    // ---- index conversion + CSR build ----
    init_kernel<<<N_NODES / 256, 256, 0, stream>>>(deg, fill, flags);
    detect_kernel<<<(E_EDGES + 255) / 256, 256, 0, stream>>>((const int*)ei_raw, E_EDGES, &flags[0]);
    detect_kernel<<<(M_MASK / 2 + 255) / 256, 256, 0, stream>>>((const int*)mask_raw, M_MASK / 2, &flags[1]);
    convert2_kernel<<<(2 * E_EDGES + M_MASK + 255) / 256, 256, 0, stream>>>(
        ei_raw, mask_raw, flags, eic, maskc);
    indeg_kernel<<<E_TOT / 256, 256, 0, stream>>>(eic, deg);
    scan_kernel<<<1, 256, 0, stream>>>(deg, rowptr);
    scatter_kernel<<<E_TOT / 256, 256, 0, stream>>>(eic, rowptr, fill, csr);

    // ---- converts + att1 algebraic path ----
    cvt_bf16_kernel<<<(N_NODES * D_IN / 4 + 255) / 256, 256, 0, stream>>>(x, xb, N_NODES * D_IN / 4);
    att1_wprep_kernel<<<(D_IN * 8) / 4, 256, 0, stream>>>(W1, att_src1, att_dst1, ws1, wd1);
    att1_gemv_kernel<<<N_NODES / 4, 256, 0, stream>>>(xb, ws1, wd1, a_s1, a_d1);
    transpose_cvt_kernel<<<dim3(F1 / 32, D_IN / 32), 256, 0, stream>>>(W1, W1t, D_IN, F1);

    // ---- layer 1 (aggregate-then-project): no h1 materialization ----
    agg8x_kernel<<<N_NODES, 192, 0, stream>>>(xb, a_s1, a_d1, rowptr, csr, xagg);
    // W2t/fcwt transposes DELIBERATELY here (independent of xagg): their
    // ~8-10us of work lets L2 drain agg8x's 100MB of dirty xagg lines so
    // gemm_bd's window doesn't carry the +30MB writeback (R15 counters).
    transpose_cvt_kernel<<<dim3(C_CH / 32, F1 / 32), 256, 0, stream>>>(W2, W2t, F1, C_CH);
    transpose_cvt_kernel<<<dim3(768 / 32, 1536 / 32), 256, 0, stream>>>(fc_w, fcwt, 1536, 768);
    gemm_bd_kernel<<<NBX_BD * NBY_BD * 8, 256, 0, stream>>>(xagg, W1t, out1, b1, N_NODES, D_IN);

    // ---- layer 2 ----  (xagg dead: region1 reused for h2 + split-K partials)
    gemm_bt_splitk_kernel<<<NBX2 * NBY2 * NSPLIT, 256, 0, stream>>>(out1, W2t, part, N_NODES, C_CH, F1);
    splitk_reduce_att_kernel<<<N_NODES, 192, 0, stream>>>(
        part, h2, att_src2, att_dst2, a_s2, a_d2);
    agg1_kernel<<<N_NODES / 4, 256, 0, stream>>>(h2, a_s2, a_d2, rowptr, csr, b2, out2);  // out1 dead

    // ---- head ----
    gatherfc_kernel<<<M_MASK, 256, 0, stream>>>(out2, xb, maskc, Afc);
    gemm_bt_kernel<<<dim3(768 / 128, M_MASK / 128), 256, 0, stream>>>(Afc, fcwt, fcout, fc_b, M_MASK, 768, 1536);
    cls_kernel<<<M_MASK / 4, 256, 0, stream>>>(fcout, cls_w, cls_b, out);
}